// Round 5
// baseline (2105.820 us; speedup 1.0000x reference)
//
#include <hip/hip_runtime.h>
#include <hip/hip_bf16.h>

#define BATCH (1u<<20)
static constexpr float EPSBN = 1e-5f;
static constexpr float INV_B = 1.0f / (float)BATCH;

// Combined gather table in ws, stride 132 floats (SQ_LDS_BANK_CONFLICT
// measured 0 with this layout, round 3/4). 16B-aligned for b128 reads.
// rows 0-14: breed1 (incl b1)  15-23: temp1  24-38: breed2  39-47: temp2
// 48-50: size1  51-53: energy1  54-56: size2  57-59: energy2
// 60-65: continuous rows (W1 rows 22,23,24,47,48,49)
// LDS rows 66 (sc1) and 67 (sh1) added after finalize1.
#define TSTR 132
#define NTABROWS 66
#define OFF_STATS  36864ULL            // 224 entries * 64B (sum @+0, sumsq @+32B)
#define OFF_PARAMS 51200ULL            // 448 floats: sc1@0 sh1@128 sc2@256 sh2@320 sc3@384 sh3@416
#define OFF_X2     65536ULL            // bf16 [64][B]
#define OFF_X3     134283264ULL        // bf16 [32][B]
#define T1_NEED    134283264ULL
#define T2_NEED    201392128ULL

struct Ptrs {
  const int *br1,*sz1,*en1,*tp1; const float *ag1,*so1,*wt1;
  const int *br2,*sz2,*en2,*tp2; const float *ag2,*so2,*wt2;
  const float *bemb,*temb;
  const float *W1,*b1,*g1,*be1;
  const float *W2,*b2,*g2,*be2;
  const float *W3,*b3,*g3,*be3;
  const float *W4,*b4;
  float* ws; float* out;
};

__device__ __forceinline__ float4 ld4(const float* p) {
  return *reinterpret_cast<const float4*>(p);
}
__device__ __forceinline__ void add4(float4& a, const float4 b) {
  a.x += b.x; a.y += b.y; a.z += b.z; a.w += b.w;
}
__device__ __forceinline__ void fma4s(float4& a, const float4 b, float s) {
  a.x = fmaf(b.x, s, a.x); a.y = fmaf(b.y, s, a.y);
  a.z = fmaf(b.z, s, a.z); a.w = fmaf(b.w, s, a.w);
}
__device__ __forceinline__ void sq4acc(float4& a, const float4 b) {
  a.x = fmaf(b.x, b.x, a.x); a.y = fmaf(b.y, b.y, a.y);
  a.z = fmaf(b.z, b.z, a.z); a.w = fmaf(b.w, b.w, a.w);
}

__device__ __forceinline__ void load_rb(const Ptrs& P, unsigned s, int rb[8], float v[6]) {
  rb[0] = P.br1[s] * TSTR;        rb[1] = (15 + P.tp1[s]) * TSTR;
  rb[2] = (24 + P.br2[s]) * TSTR; rb[3] = (39 + P.tp2[s]) * TSTR;
  rb[4] = (48 + P.sz1[s]) * TSTR; rb[5] = (51 + P.en1[s]) * TSTR;
  rb[6] = (54 + P.sz2[s]) * TSTR; rb[7] = (57 + P.en2[s]) * TSTR;
  v[0] = P.ag1[s] * (1.0f/15.0f); v[1] = P.so1[s]; v[2] = P.wt1[s] * 0.01f;
  v[3] = P.ag2[s] * (1.0f/15.0f); v[4] = P.so2[s]; v[5] = P.wt2[s] * 0.01f;
}

// stage tables (+ optionally BN1 params into rows 66/67) into LDS
__device__ __forceinline__ void stage_tab(const float* wsT, const float* params,
                                          float* Tl, bool bn1) {
  for (int i = threadIdx.x; i < NTABROWS*TSTR; i += blockDim.x) Tl[i] = wsT[i];
  if (bn1) {
    for (int i = threadIdx.x; i < 128; i += blockDim.x) {
      Tl[66*TSTR + i] = params[i];
      Tl[67*TSTR + i] = params[128 + i];
    }
  }
  __syncthreads();
}

// x2[64] (pre-BN2) from LDS tables; sc1/sh1 in LDS rows 66/67
__device__ __forceinline__ void x2_from_lds(const float* Tl, const int rb[8], const float v[6],
                                            const float* W2, const float* b2, float4 acc[16]) {
  #pragma unroll
  for (int j4 = 0; j4 < 16; ++j4) acc[j4] = ld4(b2 + j4*4);
  #pragma unroll 1
  for (int c4 = 0; c4 < 32; ++c4) {
    const int c = c4 * 4;
    float4 x = *reinterpret_cast<const float4*>(Tl + rb[0] + c);
    add4(x, *reinterpret_cast<const float4*>(Tl + rb[1] + c));
    add4(x, *reinterpret_cast<const float4*>(Tl + rb[2] + c));
    add4(x, *reinterpret_cast<const float4*>(Tl + rb[3] + c));
    add4(x, *reinterpret_cast<const float4*>(Tl + rb[4] + c));
    add4(x, *reinterpret_cast<const float4*>(Tl + rb[5] + c));
    add4(x, *reinterpret_cast<const float4*>(Tl + rb[6] + c));
    add4(x, *reinterpret_cast<const float4*>(Tl + rb[7] + c));
    #pragma unroll
    for (int m = 0; m < 6; ++m)
      fma4s(x, *reinterpret_cast<const float4*>(Tl + (60+m)*TSTR + c), v[m]);
    const float4 sc = *reinterpret_cast<const float4*>(Tl + 66*TSTR + c);
    const float4 sh = *reinterpret_cast<const float4*>(Tl + 67*TSTR + c);
    float hv[4];
    hv[0] = fmaxf(fmaf(x.x, sc.x, sh.x), 0.0f);
    hv[1] = fmaxf(fmaf(x.y, sc.y, sh.y), 0.0f);
    hv[2] = fmaxf(fmaf(x.z, sc.z, sh.z), 0.0f);
    hv[3] = fmaxf(fmaf(x.w, sc.w, sh.w), 0.0f);
    #pragma unroll
    for (int r = 0; r < 4; ++r) {
      const float hr = hv[r];
      const float4* w = reinterpret_cast<const float4*>(W2 + (c + r)*64);
      #pragma unroll
      for (int j4 = 0; j4 < 16; ++j4) fma4s(acc[j4], w[j4], hr);
    }
  }
}

// x3[32] (pre-BN3) from register x2
__device__ __forceinline__ void x3_from_acc2(const float4 acc2[16], const Ptrs& P,
                                             const float* sc2, const float* sh2,
                                             float4 acc3[8]) {
  #pragma unroll
  for (int j4 = 0; j4 < 8; ++j4) acc3[j4] = ld4(P.b3 + j4*4);
  #pragma unroll
  for (int k4 = 0; k4 < 16; ++k4) {
    const float4 a = acc2[k4];
    const float4 sc = ld4(sc2 + k4*4), sh = ld4(sh2 + k4*4);
    const float hr[4] = {
      fmaxf(fmaf(a.x, sc.x, sh.x), 0.0f),
      fmaxf(fmaf(a.y, sc.y, sh.y), 0.0f),
      fmaxf(fmaf(a.z, sc.z, sh.z), 0.0f),
      fmaxf(fmaf(a.w, sc.w, sh.w), 0.0f)};
    #pragma unroll
    for (int r = 0; r < 4; ++r) {
      const float4* w = reinterpret_cast<const float4*>(P.W3 + (k4*4 + r)*32);
      #pragma unroll
      for (int j4 = 0; j4 < 8; ++j4) fma4s(acc3[j4], w[j4], hr[r]);
    }
  }
}

// ---- wave transpose-reduce (runs ONCE per kernel now, not per sample) ----
__device__ __forceinline__ float bfly_tail32(float st[32], int lane) {
#define BSTEP(D) { const bool h = (lane & D) != 0; \
  _Pragma("unroll") \
  for (int i = 0; i < D; ++i) { \
    float mine = h ? st[i] : st[i+D]; \
    float oth  = __shfl_xor(mine, D, 64); \
    float keep = h ? st[i+D] : st[i]; \
    st[i] = keep + oth; } }
  BSTEP(16) BSTEP(8) BSTEP(4) BSTEP(2) BSTEP(1)
#undef BSTEP
  return st[0];
}

// 64-channel reduce reading vals[16] directly in the D=32 step.
template<bool SQ>
__device__ __forceinline__ float bfly64_from(const float4 acc[16], int lane) {
  float st[32];
  const bool hi = (lane & 32) != 0;
  #pragma unroll
  for (int j4 = 0; j4 < 8; ++j4) {
#define DO1(comp, idx) { \
    float lo = acc[j4].comp, hc = acc[j4+8].comp; \
    if (SQ) { lo *= lo; hc *= hc; } \
    float mine = hi ? lo : hc; \
    float keep = hi ? hc : lo; \
    st[4*j4+idx] = keep + __shfl_xor(mine, 32, 64); }
    DO1(x,0) DO1(y,1) DO1(z,2) DO1(w,3)
#undef DO1
  }
  return bfly_tail32(st, lane);
}

// 32-channel reduce (upper 32 channels implicitly zero), from vals[8].
template<bool SQ>
__device__ __forceinline__ float bfly32_from(const float4 acc3[8], int lane) {
  float st[32];
  const bool hi = (lane & 32) != 0;
  #pragma unroll
  for (int j4 = 0; j4 < 8; ++j4) {
#define DO1(comp, idx) { \
    float vv = acc3[j4].comp; \
    if (SQ) vv *= vv; \
    float mine = hi ? vv : 0.0f; \
    float keep = hi ? 0.0f : vv; \
    st[4*j4+idx] = keep + __shfl_xor(mine, 32, 64); }
    DO1(x,0) DO1(y,1) DO1(z,2) DO1(w,3)
#undef DO1
  }
  return bfly_tail32(st, lane);
}

// ---------------- kernels ----------------

__global__ __launch_bounds__(128) void k_prep(Ptrs P) {
  const int c = threadIdx.x;
  float* T = P.ws;
  for (int b = 0; b < 15; ++b) {
    float a1 = P.b1[c], a2 = 0.0f;
    #pragma unroll
    for (int e = 0; e < 8; ++e) {
      a1 = fmaf(P.bemb[b*8+e], P.W1[e*128 + c], a1);
      a2 = fmaf(P.bemb[b*8+e], P.W1[(25+e)*128 + c], a2);
    }
    T[b*TSTR + c] = a1; T[(24+b)*TSTR + c] = a2;
  }
  for (int t = 0; t < 9; ++t) {
    float a1 = 0.0f, a2 = 0.0f;
    #pragma unroll
    for (int e = 0; e < 8; ++e) {
      a1 = fmaf(P.temb[t*8+e], P.W1[(14+e)*128 + c], a1);
      a2 = fmaf(P.temb[t*8+e], P.W1[(39+e)*128 + c], a2);
    }
    T[(15+t)*TSTR + c] = a1; T[(39+t)*TSTR + c] = a2;
  }
  #pragma unroll
  for (int i = 0; i < 3; ++i) {
    T[(48+i)*TSTR + c] = P.W1[(8+i)*128 + c];
    T[(51+i)*TSTR + c] = P.W1[(11+i)*128 + c];
    T[(54+i)*TSTR + c] = P.W1[(33+i)*128 + c];
    T[(57+i)*TSTR + c] = P.W1[(36+i)*128 + c];
  }
  const int cr[6] = {22,23,24,47,48,49};
  #pragma unroll
  for (int m = 0; m < 6; ++m) T[(60+m)*TSTR + c] = P.W1[cr[m]*128 + c];
}

__global__ __launch_bounds__(256) void k_stats1(Ptrs P) {
  __shared__ __align__(16) float Tl[NTABROWS*TSTR];
  __shared__ float red[512];
  stage_tab(P.ws, nullptr, Tl, false);
  const int c = threadIdx.x & 127;
  const int half = threadIdx.x >> 7;
  float fsum = 0.0f, fsq = 0.0f;
  // 4 samples per block-iteration: half h covers {base+2h, base+2h+1}
  for (unsigned s0 = blockIdx.x*4 + half*2; s0 < BATCH; s0 += gridDim.x*4) {
    int rbA[8]; float vA[6]; load_rb(P, s0,     rbA, vA);
    int rbB[8]; float vB[6]; load_rb(P, s0 + 1, rbB, vB);
    float xA = Tl[rbA[0]+c] + Tl[rbA[1]+c] + Tl[rbA[2]+c] + Tl[rbA[3]+c]
             + Tl[rbA[4]+c] + Tl[rbA[5]+c] + Tl[rbA[6]+c] + Tl[rbA[7]+c];
    float xB = Tl[rbB[0]+c] + Tl[rbB[1]+c] + Tl[rbB[2]+c] + Tl[rbB[3]+c]
             + Tl[rbB[4]+c] + Tl[rbB[5]+c] + Tl[rbB[6]+c] + Tl[rbB[7]+c];
    #pragma unroll
    for (int m = 0; m < 6; ++m) {
      xA = fmaf(vA[m], Tl[(60+m)*TSTR + c], xA);
      xB = fmaf(vB[m], Tl[(60+m)*TSTR + c], xB);
    }
    fsum += xA + xB;
    fsq = fmaf(xA, xA, fsq); fsq = fmaf(xB, xB, fsq);
  }
  red[threadIdx.x] = fsum; red[256 + threadIdx.x] = fsq;
  __syncthreads();
  if (threadIdx.x < 128) {
    float* stat = (float*)((char*)P.ws + OFF_STATS) + (size_t)c*16;
    atomicAdd(stat,     red[c] + red[c+128]);
    atomicAdd(stat + 8, red[256+c] + red[256+c+128]);
  }
}

__global__ void k_finalize(Ptrs P, int nch, int entry0, int pofs,
                           const float* g, const float* be) {
  const int c = threadIdx.x;
  if (c >= nch) return;
  const float* stat = (const float*)((const char*)P.ws + OFF_STATS) + (size_t)(entry0 + c)*16;
  const float mean = stat[0] * INV_B;
  const float var  = stat[8] * INV_B - mean*mean;
  const float inv  = 1.0f / sqrtf(var + EPSBN);
  const float scale = g[c] * inv;
  float* params = (float*)((char*)P.ws + OFF_PARAMS);
  params[pofs + c]       = scale;
  params[pofs + nch + c] = be[c] - mean * scale;
}

template<int STORE>
__global__ __launch_bounds__(256) void k_l2(Ptrs P) {
  __shared__ __align__(16) float Tl[68*TSTR];
  __shared__ float red[512];
  const float* params = (const float*)((const char*)P.ws + OFF_PARAMS);
  stage_tab(P.ws, params, Tl, true);
  __hip_bfloat16* x2g = (__hip_bfloat16*)((char*)P.ws + OFF_X2);
  const int lane = threadIdx.x & 63;
  // per-thread channel accumulators; butterfly ONCE at the end
  float4 sums[16], sqs[16];
  #pragma unroll
  for (int j4 = 0; j4 < 16; ++j4) {
    sums[j4] = make_float4(0.f,0.f,0.f,0.f);
    sqs[j4]  = make_float4(0.f,0.f,0.f,0.f);
  }
  const unsigned stride = gridDim.x * 256;
  for (unsigned s = blockIdx.x*256 + threadIdx.x; s < BATCH; s += stride) {
    int rb[8]; float v[6];
    load_rb(P, s, rb, v);
    float4 acc[16];
    x2_from_lds(Tl, rb, v, P.W2, P.b2, acc);
    if (STORE) {
      #pragma unroll
      for (int j4 = 0; j4 < 16; ++j4) {
        x2g[(size_t)(4*j4+0)*BATCH + s] = __float2bfloat16(acc[j4].x);
        x2g[(size_t)(4*j4+1)*BATCH + s] = __float2bfloat16(acc[j4].y);
        x2g[(size_t)(4*j4+2)*BATCH + s] = __float2bfloat16(acc[j4].z);
        x2g[(size_t)(4*j4+3)*BATCH + s] = __float2bfloat16(acc[j4].w);
      }
    }
    #pragma unroll
    for (int j4 = 0; j4 < 16; ++j4) { add4(sums[j4], acc[j4]); sq4acc(sqs[j4], acc[j4]); }
  }
  const float psum = bfly64_from<false>(sums, lane);
  const float psq  = bfly64_from<false>(sqs,  lane);
  red[threadIdx.x] = psum; red[256 + threadIdx.x] = psq;
  __syncthreads();
  const int t = threadIdx.x;
  if (t < 64) {
    const float s0 = red[t] + red[t+64] + red[t+128] + red[t+192];
    const float q0 = red[256+t] + red[256+t+64] + red[256+t+128] + red[256+t+192];
    float* stat = (float*)((char*)P.ws + OFF_STATS) + (size_t)(128 + t)*16;
    atomicAdd(stat, s0); atomicAdd(stat + 8, q0);
  }
}

template<int STORE3>
__global__ __launch_bounds__(256) void k_l3_load(Ptrs P) {
  const float* params = (const float*)((const char*)P.ws + OFF_PARAMS);
  const float* sc2 = params + 256, *sh2 = params + 320;
  const __hip_bfloat16* x2g = (const __hip_bfloat16*)((const char*)P.ws + OFF_X2);
  __hip_bfloat16* x3g = (__hip_bfloat16*)((char*)P.ws + OFF_X3);
  const int lane = threadIdx.x & 63;
  float4 sums3[8], sqs3[8];
  #pragma unroll
  for (int j4 = 0; j4 < 8; ++j4) {
    sums3[j4] = make_float4(0.f,0.f,0.f,0.f);
    sqs3[j4]  = make_float4(0.f,0.f,0.f,0.f);
  }
  const unsigned stride = gridDim.x * 256;
  for (unsigned s = blockIdx.x*256 + threadIdx.x; s < BATCH; s += stride) {
    float4 acc3[8];
    #pragma unroll
    for (int j4 = 0; j4 < 8; ++j4) acc3[j4] = ld4(P.b3 + j4*4);
    #pragma unroll 4
    for (int k = 0; k < 64; ++k) {
      const float hk = fmaxf(fmaf(__bfloat162float(x2g[(size_t)k*BATCH + s]), sc2[k], sh2[k]), 0.0f);
      const float4* w = reinterpret_cast<const float4*>(P.W3 + k*32);
      #pragma unroll
      for (int j4 = 0; j4 < 8; ++j4) fma4s(acc3[j4], w[j4], hk);
    }
    if (STORE3) {
      #pragma unroll
      for (int j4 = 0; j4 < 8; ++j4) {
        x3g[(size_t)(4*j4+0)*BATCH + s] = __float2bfloat16(acc3[j4].x);
        x3g[(size_t)(4*j4+1)*BATCH + s] = __float2bfloat16(acc3[j4].y);
        x3g[(size_t)(4*j4+2)*BATCH + s] = __float2bfloat16(acc3[j4].z);
        x3g[(size_t)(4*j4+3)*BATCH + s] = __float2bfloat16(acc3[j4].w);
      }
    }
    #pragma unroll
    for (int j4 = 0; j4 < 8; ++j4) { add4(sums3[j4], acc3[j4]); sq4acc(sqs3[j4], acc3[j4]); }
  }
  const float psum = bfly32_from<false>(sums3, lane);
  const float psq  = bfly32_from<false>(sqs3,  lane);
  __shared__ float red[512];
  red[threadIdx.x] = psum; red[256 + threadIdx.x] = psq;
  __syncthreads();
  const int t = threadIdx.x;
  if (t < 32) {
    const float s0 = red[t] + red[t+64] + red[t+128] + red[t+192];
    const float q0 = red[256+t] + red[256+t+64] + red[256+t+128] + red[256+t+192];
    float* stat = (float*)((char*)P.ws + OFF_STATS) + (size_t)(192 + t)*16;
    atomicAdd(stat, s0); atomicAdd(stat + 8, q0);
  }
}

__global__ __launch_bounds__(256) void k_l4_load3(Ptrs P) {
  const float* params = (const float*)((const char*)P.ws + OFF_PARAMS);
  const float* sc3 = params + 384, *sh3 = params + 416;
  const __hip_bfloat16* x3g = (const __hip_bfloat16*)((const char*)P.ws + OFF_X3);
  const unsigned stride = gridDim.x * 256;
  for (unsigned s = blockIdx.x*256 + threadIdx.x; s < BATCH; s += stride) {
    float z = P.b4[0];
    #pragma unroll 8
    for (int k = 0; k < 32; ++k) {
      const float hk = fmaxf(fmaf(__bfloat162float(x3g[(size_t)k*BATCH + s]), sc3[k], sh3[k]), 0.0f);
      z = fmaf(hk, P.W4[k], z);
    }
    P.out[s] = 1.0f / (1.0f + __expf(-z));
  }
}

__global__ __launch_bounds__(256) void k_l4_from2(Ptrs P) {
  const float* params = (const float*)((const char*)P.ws + OFF_PARAMS);
  const float* sc2 = params + 256, *sh2 = params + 320;
  const float* sc3 = params + 384, *sh3 = params + 416;
  const __hip_bfloat16* x2g = (const __hip_bfloat16*)((const char*)P.ws + OFF_X2);
  const unsigned stride = gridDim.x * 256;
  for (unsigned s = blockIdx.x*256 + threadIdx.x; s < BATCH; s += stride) {
    float4 acc3[8];
    #pragma unroll
    for (int j4 = 0; j4 < 8; ++j4) acc3[j4] = ld4(P.b3 + j4*4);
    #pragma unroll 4
    for (int k = 0; k < 64; ++k) {
      const float hk = fmaxf(fmaf(__bfloat162float(x2g[(size_t)k*BATCH + s]), sc2[k], sh2[k]), 0.0f);
      const float4* w = reinterpret_cast<const float4*>(P.W3 + k*32);
      #pragma unroll
      for (int j4 = 0; j4 < 8; ++j4) fma4s(acc3[j4], w[j4], hk);
    }
    float z = P.b4[0];
    #pragma unroll
    for (int k4 = 0; k4 < 8; ++k4) {
      const float4 a = acc3[k4];
      const float4 sc = ld4(sc3 + k4*4), sh = ld4(sh3 + k4*4);
      z = fmaf(fmaxf(fmaf(a.x, sc.x, sh.x), 0.0f), P.W4[k4*4+0], z);
      z = fmaf(fmaxf(fmaf(a.y, sc.y, sh.y), 0.0f), P.W4[k4*4+1], z);
      z = fmaf(fmaxf(fmaf(a.z, sc.z, sh.z), 0.0f), P.W4[k4*4+2], z);
      z = fmaf(fmaxf(fmaf(a.w, sc.w, sh.w), 0.0f), P.W4[k4*4+3], z);
    }
    P.out[s] = 1.0f / (1.0f + __expf(-z));
  }
}

__global__ __launch_bounds__(256) void k_l3_rec(Ptrs P) {
  __shared__ __align__(16) float Tl[68*TSTR];
  __shared__ float red[512];
  const float* params = (const float*)((const char*)P.ws + OFF_PARAMS);
  stage_tab(P.ws, params, Tl, true);
  const float* sc2 = params + 256, *sh2 = params + 320;
  const int lane = threadIdx.x & 63;
  float4 sums3[8], sqs3[8];
  #pragma unroll
  for (int j4 = 0; j4 < 8; ++j4) {
    sums3[j4] = make_float4(0.f,0.f,0.f,0.f);
    sqs3[j4]  = make_float4(0.f,0.f,0.f,0.f);
  }
  const unsigned stride = gridDim.x * 256;
  for (unsigned s = blockIdx.x*256 + threadIdx.x; s < BATCH; s += stride) {
    int rb[8]; float v[6];
    load_rb(P, s, rb, v);
    float4 acc2[16];
    x2_from_lds(Tl, rb, v, P.W2, P.b2, acc2);
    float4 acc3[8];
    x3_from_acc2(acc2, P, sc2, sh2, acc3);
    #pragma unroll
    for (int j4 = 0; j4 < 8; ++j4) { add4(sums3[j4], acc3[j4]); sq4acc(sqs3[j4], acc3[j4]); }
  }
  const float psum = bfly32_from<false>(sums3, lane);
  const float psq  = bfly32_from<false>(sqs3,  lane);
  red[threadIdx.x] = psum; red[256 + threadIdx.x] = psq;
  __syncthreads();
  const int t = threadIdx.x;
  if (t < 32) {
    const float s0 = red[t] + red[t+64] + red[t+128] + red[t+192];
    const float q0 = red[256+t] + red[256+t+64] + red[256+t+128] + red[256+t+192];
    float* stat = (float*)((char*)P.ws + OFF_STATS) + (size_t)(192 + t)*16;
    atomicAdd(stat, s0); atomicAdd(stat + 8, q0);
  }
}

__global__ __launch_bounds__(256) void k_l4_rec(Ptrs P) {
  __shared__ __align__(16) float Tl[68*TSTR];
  const float* params = (const float*)((const char*)P.ws + OFF_PARAMS);
  stage_tab(P.ws, params, Tl, true);
  const float* sc2 = params + 256, *sh2 = params + 320;
  const float* sc3 = params + 384, *sh3 = params + 416;
  const unsigned stride = gridDim.x * 256;
  for (unsigned s = blockIdx.x*256 + threadIdx.x; s < BATCH; s += stride) {
    int rb[8]; float v[6];
    load_rb(P, s, rb, v);
    float4 acc2[16];
    x2_from_lds(Tl, rb, v, P.W2, P.b2, acc2);
    float4 acc3[8];
    x3_from_acc2(acc2, P, sc2, sh2, acc3);
    float z = P.b4[0];
    #pragma unroll
    for (int k4 = 0; k4 < 8; ++k4) {
      const float4 a = acc3[k4];
      const float4 sc = ld4(sc3 + k4*4), sh = ld4(sh3 + k4*4);
      z = fmaf(fmaxf(fmaf(a.x, sc.x, sh.x), 0.0f), P.W4[k4*4+0], z);
      z = fmaf(fmaxf(fmaf(a.y, sc.y, sh.y), 0.0f), P.W4[k4*4+1], z);
      z = fmaf(fmaxf(fmaf(a.z, sc.z, sh.z), 0.0f), P.W4[k4*4+2], z);
      z = fmaf(fmaxf(fmaf(a.w, sc.w, sh.w), 0.0f), P.W4[k4*4+3], z);
    }
    P.out[s] = 1.0f / (1.0f + __expf(-z));
  }
}

// ---------------- host ----------------

extern "C" void kernel_launch(void* const* d_in, const int* in_sizes, int n_in,
                              void* d_out, int out_size, void* d_ws, size_t ws_size,
                              hipStream_t stream) {
  Ptrs P;
  P.br1 = (const int*)d_in[0];  P.sz1 = (const int*)d_in[1];
  P.en1 = (const int*)d_in[2];  P.tp1 = (const int*)d_in[3];
  P.ag1 = (const float*)d_in[4]; P.so1 = (const float*)d_in[5]; P.wt1 = (const float*)d_in[6];
  P.br2 = (const int*)d_in[7];  P.sz2 = (const int*)d_in[8];
  P.en2 = (const int*)d_in[9];  P.tp2 = (const int*)d_in[10];
  P.ag2 = (const float*)d_in[11]; P.so2 = (const float*)d_in[12]; P.wt2 = (const float*)d_in[13];
  P.bemb = (const float*)d_in[14]; P.temb = (const float*)d_in[15];
  P.W1 = (const float*)d_in[16]; P.b1 = (const float*)d_in[17];
  P.g1 = (const float*)d_in[18]; P.be1 = (const float*)d_in[19];
  P.W2 = (const float*)d_in[20]; P.b2 = (const float*)d_in[21];
  P.g2 = (const float*)d_in[22]; P.be2 = (const float*)d_in[23];
  P.W3 = (const float*)d_in[24]; P.b3 = (const float*)d_in[25];
  P.g3 = (const float*)d_in[26]; P.be3 = (const float*)d_in[27];
  P.W4 = (const float*)d_in[28]; P.b4 = (const float*)d_in[29];
  P.ws = (float*)d_ws; P.out = (float*)d_out;

  const bool t1 = ws_size >= T1_NEED;
  const bool t2 = ws_size >= T2_NEED;

  hipMemsetAsync((char*)d_ws + OFF_STATS, 0, 224*64, stream);
  hipLaunchKernelGGL(k_prep, dim3(1), dim3(128), 0, stream, P);
  hipLaunchKernelGGL(k_stats1, dim3(1024), dim3(256), 0, stream, P);
  hipLaunchKernelGGL(k_finalize, dim3(1), dim3(128), 0, stream, P, 128, 0, 0, P.g1, P.be1);
  if (t2) {
    hipLaunchKernelGGL((k_l2<1>), dim3(1024), dim3(256), 0, stream, P);
    hipLaunchKernelGGL(k_finalize, dim3(1), dim3(64), 0, stream, P, 64, 128, 256, P.g2, P.be2);
    hipLaunchKernelGGL((k_l3_load<1>), dim3(1024), dim3(256), 0, stream, P);
    hipLaunchKernelGGL(k_finalize, dim3(1), dim3(32), 0, stream, P, 32, 192, 384, P.g3, P.be3);
    hipLaunchKernelGGL(k_l4_load3, dim3(2048), dim3(256), 0, stream, P);
  } else if (t1) {
    hipLaunchKernelGGL((k_l2<1>), dim3(1024), dim3(256), 0, stream, P);
    hipLaunchKernelGGL(k_finalize, dim3(1), dim3(64), 0, stream, P, 64, 128, 256, P.g2, P.be2);
    hipLaunchKernelGGL((k_l3_load<0>), dim3(1024), dim3(256), 0, stream, P);
    hipLaunchKernelGGL(k_finalize, dim3(1), dim3(32), 0, stream, P, 32, 192, 384, P.g3, P.be3);
    hipLaunchKernelGGL(k_l4_from2, dim3(2048), dim3(256), 0, stream, P);
  } else {
    hipLaunchKernelGGL((k_l2<0>), dim3(1024), dim3(256), 0, stream, P);
    hipLaunchKernelGGL(k_finalize, dim3(1), dim3(64), 0, stream, P, 64, 128, 256, P.g2, P.be2);
    hipLaunchKernelGGL(k_l3_rec, dim3(1024), dim3(256), 0, stream, P);
    hipLaunchKernelGGL(k_finalize, dim3(1), dim3(32), 0, stream, P, 32, 192, 384, P.g3, P.be3);
    hipLaunchKernelGGL(k_l4_rec, dim3(2048), dim3(256), 0, stream, P);
  }
}

// Round 6
// 873.562 us; speedup vs baseline: 2.4106x; 2.4106x over previous
//
#include <hip/hip_runtime.h>
#include <hip/hip_bf16.h>

#define BATCH (1u<<20)
static constexpr float EPSBN = 1e-5f;
static constexpr float INV_B = 1.0f / (float)BATCH;

typedef unsigned int   uint;
typedef unsigned short ushort;

// f32 gather tables at ws+0, stride 132 floats (conflict-measured-0 layout).
// rows 0-14 breed1(+b1) | 15-23 temp1 | 24-38 breed2 | 39-47 temp2
// 48-50 sz1 | 51-53 en1 | 54-56 sz2 | 57-59 en2 | 60-65 continuous
// rows 66/67 = sc1/sh1 (staged into LDS for rec path only)
#define TSTR 132
#define NTABROWS 66
#define TBSTR 136                      // bf16 table stride (elems); 272B rows rotate banks
#define OFF_TBF    36864ULL            // bf16 tables [66][136] -> 17952 B
#define OFF_W2F    55296ULL            // W2^T A-frags bf16: 16 frag * 64 lane * 16B = 16 KB
#define OFF_W3F    71680ULL            // W3^T A-frags bf16: 4 KB
#define OFF_STATS  75776ULL            // 224 entries * 64B (sum @+0, sumsq @+32B)
#define OFF_PARAMS 90112ULL            // 448 f32: sc1@0 sh1@128 sc2@256 sh2@320 sc3@384 sh3@416
#define OFF_X2     98304ULL            // bf16 [B][64], 128B rows; x3 aliased into first 64B
#define T1_NEED    (98304ULL + 134217728ULL)

struct Ptrs {
  const int *br1,*sz1,*en1,*tp1; const float *ag1,*so1,*wt1;
  const int *br2,*sz2,*en2,*tp2; const float *ag2,*so2,*wt2;
  const float *bemb,*temb;
  const float *W1,*b1,*g1,*be1;
  const float *W2,*b2,*g2,*be2;
  const float *W3,*b3,*g3,*be3;
  const float *W4,*b4;
  float* ws; float* out;
};

typedef __attribute__((ext_vector_type(8))) short bf16x8;
typedef __attribute__((ext_vector_type(4))) float f32x4;

__device__ __forceinline__ float4 ld4(const float* p) {
  return *reinterpret_cast<const float4*>(p);
}
__device__ __forceinline__ void add4(float4& a, const float4 b) {
  a.x += b.x; a.y += b.y; a.z += b.z; a.w += b.w;
}
__device__ __forceinline__ void fma4s(float4& a, const float4 b, float s) {
  a.x = fmaf(b.x, s, a.x); a.y = fmaf(b.y, s, a.y);
  a.z = fmaf(b.z, s, a.z); a.w = fmaf(b.w, s, a.w);
}

__device__ __forceinline__ ushort bfb(float f) {
  union { __hip_bfloat16 h; ushort u; } cv; cv.h = __float2bfloat16(f); return cv.u;
}
__device__ __forceinline__ uint pk2(float a, float b) {
  return ((uint)bfb(b) << 16) | (uint)bfb(a);
}
__device__ __forceinline__ bf16x8 ldfrag(const void* p) {
  union { uint4 u; bf16x8 v; } cv; cv.u = *reinterpret_cast<const uint4*>(p); return cv.v;
}
__device__ __forceinline__ bf16x8 mkfrag(uint a, uint b, uint c, uint d) {
  union { uint4 u; bf16x8 v; } cv; cv.u = make_uint4(a,b,c,d); return cv.v;
}
__device__ __forceinline__ float bflo(uint w) { return __uint_as_float(w << 16); }
__device__ __forceinline__ float bfhi(uint w) { return __uint_as_float(w & 0xffff0000u); }

struct SIdx { int r[8]; float v[6]; };
__device__ __forceinline__ SIdx load_idx(const Ptrs& P, unsigned s) {
  SIdx o;
  o.r[0] = P.br1[s];      o.r[1] = 15 + P.tp1[s];
  o.r[2] = 24 + P.br2[s]; o.r[3] = 39 + P.tp2[s];
  o.r[4] = 48 + P.sz1[s]; o.r[5] = 51 + P.en1[s];
  o.r[6] = 54 + P.sz2[s]; o.r[7] = 57 + P.en2[s];
  o.v[0] = P.ag1[s]*(1.0f/15.0f); o.v[1] = P.so1[s]; o.v[2] = P.wt1[s]*0.01f;
  o.v[3] = P.ag2[s]*(1.0f/15.0f); o.v[4] = P.so2[s]; o.v[5] = P.wt2[s]*0.01f;
  return o;
}

// rec-path helpers (round-4/5 proven) ---------------------------------------
__device__ __forceinline__ void load_rb(const Ptrs& P, unsigned s, int rb[8], float v[6]) {
  SIdx o = load_idx(P, s);
  #pragma unroll
  for (int i = 0; i < 8; ++i) rb[i] = o.r[i]*TSTR;
  #pragma unroll
  for (int i = 0; i < 6; ++i) v[i] = o.v[i];
}

__device__ __forceinline__ void stage_tab(const float* wsT, const float* params,
                                          float* Tl, bool bn1) {
  for (int i = threadIdx.x; i < NTABROWS*TSTR; i += blockDim.x) Tl[i] = wsT[i];
  if (bn1) {
    for (int i = threadIdx.x; i < 128; i += blockDim.x) {
      Tl[66*TSTR + i] = params[i];
      Tl[67*TSTR + i] = params[128 + i];
    }
  }
  __syncthreads();
}

__device__ __forceinline__ void x2_from_lds(const float* Tl, const int rb[8], const float v[6],
                                            const float* W2, const float* b2, float4 acc[16]) {
  #pragma unroll
  for (int j4 = 0; j4 < 16; ++j4) acc[j4] = ld4(b2 + j4*4);
  #pragma unroll 1
  for (int c4 = 0; c4 < 32; ++c4) {
    const int c = c4 * 4;
    float4 x = *reinterpret_cast<const float4*>(Tl + rb[0] + c);
    add4(x, *reinterpret_cast<const float4*>(Tl + rb[1] + c));
    add4(x, *reinterpret_cast<const float4*>(Tl + rb[2] + c));
    add4(x, *reinterpret_cast<const float4*>(Tl + rb[3] + c));
    add4(x, *reinterpret_cast<const float4*>(Tl + rb[4] + c));
    add4(x, *reinterpret_cast<const float4*>(Tl + rb[5] + c));
    add4(x, *reinterpret_cast<const float4*>(Tl + rb[6] + c));
    add4(x, *reinterpret_cast<const float4*>(Tl + rb[7] + c));
    #pragma unroll
    for (int m = 0; m < 6; ++m)
      fma4s(x, *reinterpret_cast<const float4*>(Tl + (60+m)*TSTR + c), v[m]);
    const float4 sc = *reinterpret_cast<const float4*>(Tl + 66*TSTR + c);
    const float4 sh = *reinterpret_cast<const float4*>(Tl + 67*TSTR + c);
    float hv[4];
    hv[0] = fmaxf(fmaf(x.x, sc.x, sh.x), 0.0f);
    hv[1] = fmaxf(fmaf(x.y, sc.y, sh.y), 0.0f);
    hv[2] = fmaxf(fmaf(x.z, sc.z, sh.z), 0.0f);
    hv[3] = fmaxf(fmaf(x.w, sc.w, sh.w), 0.0f);
    #pragma unroll
    for (int r = 0; r < 4; ++r) {
      const float hr = hv[r];
      const float4* w = reinterpret_cast<const float4*>(W2 + (c + r)*64);
      #pragma unroll
      for (int j4 = 0; j4 < 16; ++j4) fma4s(acc[j4], w[j4], hr);
    }
  }
}

__device__ __forceinline__ void x3_from_acc2(const float4 acc2[16], const Ptrs& P,
                                             const float* sc2, const float* sh2,
                                             float4 acc3[8]) {
  #pragma unroll
  for (int j4 = 0; j4 < 8; ++j4) acc3[j4] = ld4(P.b3 + j4*4);
  #pragma unroll
  for (int k4 = 0; k4 < 16; ++k4) {
    const float4 a = acc2[k4];
    const float4 sc = ld4(sc2 + k4*4), sh = ld4(sh2 + k4*4);
    const float hr[4] = {
      fmaxf(fmaf(a.x, sc.x, sh.x), 0.0f),
      fmaxf(fmaf(a.y, sc.y, sh.y), 0.0f),
      fmaxf(fmaf(a.z, sc.z, sh.z), 0.0f),
      fmaxf(fmaf(a.w, sc.w, sh.w), 0.0f)};
    #pragma unroll
    for (int r = 0; r < 4; ++r) {
      const float4* w = reinterpret_cast<const float4*>(P.W3 + (k4*4 + r)*32);
      #pragma unroll
      for (int j4 = 0; j4 < 8; ++j4) fma4s(acc3[j4], w[j4], hr[r]);
    }
  }
}

__device__ __forceinline__ float bfly_tail32(float st[32], int lane) {
#define BSTEP(D) { const bool h = (lane & D) != 0; \
  _Pragma("unroll") \
  for (int i = 0; i < D; ++i) { \
    float mine = h ? st[i] : st[i+D]; \
    float oth  = __shfl_xor(mine, D, 64); \
    float keep = h ? st[i+D] : st[i]; \
    st[i] = keep + oth; } }
  BSTEP(16) BSTEP(8) BSTEP(4) BSTEP(2) BSTEP(1)
#undef BSTEP
  return st[0];
}

template<bool SQ>
__device__ __forceinline__ float bfly64_from(const float4 acc[16], int lane) {
  float st[32];
  const bool hi = (lane & 32) != 0;
  #pragma unroll
  for (int j4 = 0; j4 < 8; ++j4) {
#define DO1(comp, idx) { \
    float lo = acc[j4].comp, hc = acc[j4+8].comp; \
    if (SQ) { lo *= lo; hc *= hc; } \
    float mine = hi ? lo : hc; \
    float keep = hi ? hc : lo; \
    st[4*j4+idx] = keep + __shfl_xor(mine, 32, 64); }
    DO1(x,0) DO1(y,1) DO1(z,2) DO1(w,3)
#undef DO1
  }
  return bfly_tail32(st, lane);
}

template<bool SQ>
__device__ __forceinline__ float bfly32_from(const float4 acc3[8], int lane) {
  float st[32];
  const bool hi = (lane & 32) != 0;
  #pragma unroll
  for (int j4 = 0; j4 < 8; ++j4) {
#define DO1(comp, idx) { \
    float vv = acc3[j4].comp; \
    if (SQ) vv *= vv; \
    float mine = hi ? vv : 0.0f; \
    float keep = hi ? 0.0f : vv; \
    st[4*j4+idx] = keep + __shfl_xor(mine, 32, 64); }
    DO1(x,0) DO1(y,1) DO1(z,2) DO1(w,3)
#undef DO1
  }
  return bfly_tail32(st, lane);
}

// ---------------- kernels ----------------

__global__ __launch_bounds__(256) void k_prep(Ptrs P) {
  const int t = threadIdx.x;
  float* T = P.ws;
  if (t < 128) {
    const int c = t;
    for (int b = 0; b < 15; ++b) {
      float a1 = P.b1[c], a2 = 0.0f;
      #pragma unroll
      for (int e = 0; e < 8; ++e) {
        a1 = fmaf(P.bemb[b*8+e], P.W1[e*128 + c], a1);
        a2 = fmaf(P.bemb[b*8+e], P.W1[(25+e)*128 + c], a2);
      }
      T[b*TSTR + c] = a1; T[(24+b)*TSTR + c] = a2;
    }
    for (int tt = 0; tt < 9; ++tt) {
      float a1 = 0.0f, a2 = 0.0f;
      #pragma unroll
      for (int e = 0; e < 8; ++e) {
        a1 = fmaf(P.temb[tt*8+e], P.W1[(14+e)*128 + c], a1);
        a2 = fmaf(P.temb[tt*8+e], P.W1[(39+e)*128 + c], a2);
      }
      T[(15+tt)*TSTR + c] = a1; T[(39+tt)*TSTR + c] = a2;
    }
    #pragma unroll
    for (int i = 0; i < 3; ++i) {
      T[(48+i)*TSTR + c] = P.W1[(8+i)*128 + c];
      T[(51+i)*TSTR + c] = P.W1[(11+i)*128 + c];
      T[(54+i)*TSTR + c] = P.W1[(33+i)*128 + c];
      T[(57+i)*TSTR + c] = P.W1[(36+i)*128 + c];
    }
    const int cr[6] = {22,23,24,47,48,49};
    #pragma unroll
    for (int m = 0; m < 6; ++m) T[(60+m)*TSTR + c] = P.W1[cr[m]*128 + c];
  }
  __syncthreads();
  // bf16 copy of tables (stats1 path)
  __hip_bfloat16* Tb = (__hip_bfloat16*)((char*)P.ws + OFF_TBF);
  for (int idx = t; idx < 66*128; idx += 256) {
    const int r = idx >> 7, c = idx & 127;
    Tb[r*TBSTR + c] = __float2bfloat16(T[r*TSTR + c]);
  }
  // W2^T MFMA A-frags: frag fid=(mt*4+kk), lane l=(q<<4|m): e -> W2[kk*32+8q+e][16mt+m]
  __hip_bfloat16* w2f = (__hip_bfloat16*)((char*)P.ws + OFF_W2F);
  for (int slot = t; slot < 1024; slot += 256) {
    const int fid = slot >> 6, l = slot & 63;
    const int mt = fid >> 2, kk = fid & 3, q = l >> 4, m = l & 15;
    #pragma unroll
    for (int e = 0; e < 8; ++e)
      w2f[slot*8 + e] = __float2bfloat16(P.W2[(kk*32 + 8*q + e)*64 + 16*mt + m]);
  }
  // W3^T A-frags: fid=(mt*2+kk)
  __hip_bfloat16* w3f = (__hip_bfloat16*)((char*)P.ws + OFF_W3F);
  for (int slot = t; slot < 256; slot += 256) {
    const int fid = slot >> 6, l = slot & 63;
    const int mt = fid >> 1, kk = fid & 1, q = l >> 4, m = l & 15;
    #pragma unroll
    for (int e = 0; e < 8; ++e)
      w3f[slot*8 + e] = __float2bfloat16(P.W3[(kk*32 + 8*q + e)*32 + 16*mt + m]);
  }
}

// BN1 stats: lane = (sample s=it*16+m16, k-slice q); bf16 tables in LDS.
__global__ __launch_bounds__(256) void k_stats1(Ptrs P) {
  __shared__ __align__(16) __hip_bfloat16 Tb[60*TBSTR];
  __shared__ float sred[256];
  {
    const uint* src = (const uint*)((const char*)P.ws + OFF_TBF);
    uint* dst = (uint*)Tb;
    for (int i = threadIdx.x; i < 60*TBSTR/2; i += 256) dst[i] = src[i];
  }
  sred[threadIdx.x] = 0.f;
  __syncthreads();
  const int lane = threadIdx.x & 63;
  const int q = lane >> 4, m16 = lane & 15;
  const __hip_bfloat16* Tbc = (const __hip_bfloat16*)((const char*)P.ws + OFF_TBF);
  const unsigned wv = (blockIdx.x*256 + threadIdx.x) >> 6;
  const unsigned nw = (gridDim.x*256) >> 6;
  float sums[32], sqs[32];
  #pragma unroll
  for (int i = 0; i < 32; ++i) { sums[i] = 0.f; sqs[i] = 0.f; }
  for (unsigned it = wv; it < (BATCH>>4); it += nw) {
    const unsigned s = it*16 + m16;
    const SIdx o = load_idx(P, s);
    #pragma unroll
    for (int kk = 0; kk < 4; ++kk) {
      const int c = kk*32 + 8*q;
      float x[8];
      #pragma unroll
      for (int e = 0; e < 8; ++e) x[e] = 0.f;
      #pragma unroll
      for (int g = 0; g < 8; ++g) {
        const uint4 u = *reinterpret_cast<const uint4*>(Tb + o.r[g]*TBSTR + c);
        const uint w[4] = {u.x,u.y,u.z,u.w};
        #pragma unroll
        for (int j = 0; j < 4; ++j) { x[2*j] += bflo(w[j]); x[2*j+1] += bfhi(w[j]); }
      }
      #pragma unroll
      for (int m = 0; m < 6; ++m) {
        const uint4 u = *reinterpret_cast<const uint4*>(Tbc + (60+m)*TBSTR + c);
        const uint w[4] = {u.x,u.y,u.z,u.w};
        #pragma unroll
        for (int j = 0; j < 4; ++j) {
          x[2*j]   = fmaf(bflo(w[j]), o.v[m], x[2*j]);
          x[2*j+1] = fmaf(bfhi(w[j]), o.v[m], x[2*j+1]);
        }
      }
      #pragma unroll
      for (int e = 0; e < 8; ++e) {
        sums[kk*8+e] += x[e];
        sqs[kk*8+e]  = fmaf(x[e], x[e], sqs[kk*8+e]);
      }
    }
  }
  #pragma unroll
  for (int d = 1; d <= 8; d <<= 1) {
    #pragma unroll
    for (int i = 0; i < 32; ++i) {
      sums[i] += __shfl_xor(sums[i], d, 64);
      sqs[i]  += __shfl_xor(sqs[i],  d, 64);
    }
  }
  if (m16 == 0) {
    #pragma unroll
    for (int i = 0; i < 32; ++i) {
      const int ch = (i >> 3)*32 + 8*q + (i & 7);
      atomicAdd(&sred[ch], sums[i]);
      atomicAdd(&sred[128+ch], sqs[i]);
    }
  }
  __syncthreads();
  if (threadIdx.x < 128) {
    float* stat = (float*)((char*)P.ws + OFF_STATS) + (size_t)threadIdx.x*16;
    atomicAdd(stat,     sred[threadIdx.x]);
    atomicAdd(stat + 8, sred[128+threadIdx.x]);
  }
}

__global__ void k_finalize(Ptrs P, int nch, int entry0, int pofs,
                           const float* g, const float* be) {
  const int c = threadIdx.x;
  if (c >= nch) return;
  const float* stat = (const float*)((const char*)P.ws + OFF_STATS) + (size_t)(entry0 + c)*16;
  const float mean = stat[0] * INV_B;
  const float var  = stat[8] * INV_B - mean*mean;
  const float inv  = 1.0f / sqrtf(var + EPSBN);
  const float scale = g[c] * inv;
  float* params = (float*)((char*)P.ws + OFF_PARAMS);
  params[pofs + c]       = scale;
  params[pofs + nch + c] = be[c] - mean * scale;
}

// Layer2 MFMA: per 16-sample tile, lane=(s=m16, k-slice q). 16 MFMA/tile.
__global__ __launch_bounds__(256) void k_l2m(Ptrs P) {
  __shared__ __align__(16) float Tl[60*TSTR];
  __shared__ float sred[128];
  sred[threadIdx.x & 127] = 0.f;
  for (int i = threadIdx.x; i < 60*TSTR; i += 256) Tl[i] = P.ws[i];
  __syncthreads();
  const float* params = (const float*)((const char*)P.ws + OFF_PARAMS);
  const float* sc1 = params, *sh1 = params + 128;
  const float* contT = P.ws;            // rows 60..65 read from global (L1-hot)
  const int lane = threadIdx.x & 63;
  const int q = lane >> 4, m16 = lane & 15;
  const char* w2fB = (const char*)P.ws + OFF_W2F;
  char* x2B = (char*)P.ws + OFF_X2;
  float sums[16], sqs[16];
  #pragma unroll
  for (int i = 0; i < 16; ++i) { sums[i] = 0.f; sqs[i] = 0.f; }
  const unsigned wv = (blockIdx.x*256 + threadIdx.x) >> 6;
  const unsigned nw = (gridDim.x*256) >> 6;
  for (unsigned it = wv; it < (BATCH>>4); it += nw) {
    const unsigned s = it*16 + m16;
    int rb[8]; float v[6];
    {
      const SIdx o = load_idx(P, s);
      #pragma unroll
      for (int i = 0; i < 8; ++i) rb[i] = o.r[i]*TSTR;
      #pragma unroll
      for (int i = 0; i < 6; ++i) v[i] = o.v[i];
    }
    f32x4 D[4];
    #pragma unroll
    for (int mt = 0; mt < 4; ++mt) {
      const float4 b = ld4(P.b2 + 16*mt + 4*q);
      D[mt][0] = b.x; D[mt][1] = b.y; D[mt][2] = b.z; D[mt][3] = b.w;
    }
    #pragma unroll
    for (int kk = 0; kk < 4; ++kk) {
      const int c = kk*32 + 8*q;
      float4 xa = ld4(Tl + rb[0] + c);
      float4 xb = ld4(Tl + rb[0] + c + 4);
      #pragma unroll
      for (int g = 1; g < 8; ++g) {
        add4(xa, ld4(Tl + rb[g] + c));
        add4(xb, ld4(Tl + rb[g] + c + 4));
      }
      #pragma unroll
      for (int m = 0; m < 6; ++m) {
        fma4s(xa, ld4(contT + (60+m)*TSTR + c), v[m]);
        fma4s(xb, ld4(contT + (60+m)*TSTR + c + 4), v[m]);
      }
      const float4 sca = ld4(sc1 + c), sha = ld4(sh1 + c);
      const float4 scb = ld4(sc1 + c + 4), shb = ld4(sh1 + c + 4);
      const float h0 = fmaxf(fmaf(xa.x, sca.x, sha.x), 0.f);
      const float h1 = fmaxf(fmaf(xa.y, sca.y, sha.y), 0.f);
      const float h2 = fmaxf(fmaf(xa.z, sca.z, sha.z), 0.f);
      const float h3 = fmaxf(fmaf(xa.w, sca.w, sha.w), 0.f);
      const float h4 = fmaxf(fmaf(xb.x, scb.x, shb.x), 0.f);
      const float h5 = fmaxf(fmaf(xb.y, scb.y, shb.y), 0.f);
      const float h6 = fmaxf(fmaf(xb.z, scb.z, shb.z), 0.f);
      const float h7 = fmaxf(fmaf(xb.w, scb.w, shb.w), 0.f);
      const bf16x8 bf = mkfrag(pk2(h0,h1), pk2(h2,h3), pk2(h4,h5), pk2(h6,h7));
      #pragma unroll
      for (int mt = 0; mt < 4; ++mt) {
        const bf16x8 af = ldfrag(w2fB + (size_t)((mt*4+kk)*64 + lane)*16);
        D[mt] = __builtin_amdgcn_mfma_f32_16x16x32_bf16(af, bf, D[mt], 0, 0, 0);
      }
    }
    #pragma unroll
    for (int mt = 0; mt < 4; ++mt) {
      #pragma unroll
      for (int r = 0; r < 4; ++r) {
        const float d = D[mt][r];
        sums[mt*4+r] += d;
        sqs[mt*4+r]  = fmaf(d, d, sqs[mt*4+r]);
      }
      const uint lo = pk2(D[mt][0], D[mt][1]);
      const uint hi = pk2(D[mt][2], D[mt][3]);
      *reinterpret_cast<uint2*>(x2B + (size_t)s*128 + (16*mt + 4*q)*2) = make_uint2(lo, hi);
    }
  }
  #pragma unroll
  for (int d = 1; d <= 8; d <<= 1) {
    #pragma unroll
    for (int i = 0; i < 16; ++i) {
      sums[i] += __shfl_xor(sums[i], d, 64);
      sqs[i]  += __shfl_xor(sqs[i],  d, 64);
    }
  }
  if (m16 == 0) {
    #pragma unroll
    for (int i = 0; i < 16; ++i) {
      const int ch = 16*(i >> 2) + 4*q + (i & 3);
      atomicAdd(&sred[ch], sums[i]);
      atomicAdd(&sred[64+ch], sqs[i]);
    }
  }
  __syncthreads();
  if (threadIdx.x < 64) {
    float* stat = (float*)((char*)P.ws + OFF_STATS) + (size_t)(128 + threadIdx.x)*16;
    atomicAdd(stat, sred[threadIdx.x]);
    atomicAdd(stat + 8, sred[64+threadIdx.x]);
  }
}

// Layer3 MFMA: reads sample-major x2 bf16, writes x3 into row front (alias-safe).
__global__ __launch_bounds__(256) void k_l3m(Ptrs P) {
  __shared__ float sred[64];
  if (threadIdx.x < 64) sred[threadIdx.x] = 0.f;
  __syncthreads();
  const float* params = (const float*)((const char*)P.ws + OFF_PARAMS);
  const float* sc2 = params + 256, *sh2 = params + 320;
  const int lane = threadIdx.x & 63;
  const int q = lane >> 4, m16 = lane & 15;
  const char* w3fB = (const char*)P.ws + OFF_W3F;
  char* xB = (char*)P.ws + OFF_X2;
  float sums[8], sqs[8];
  #pragma unroll
  for (int i = 0; i < 8; ++i) { sums[i] = 0.f; sqs[i] = 0.f; }
  const unsigned wv = (blockIdx.x*256 + threadIdx.x) >> 6;
  const unsigned nw = (gridDim.x*256) >> 6;
  for (unsigned it = wv; it < (BATCH>>4); it += nw) {
    const unsigned s = it*16 + m16;
    f32x4 D[2];
    #pragma unroll
    for (int mt = 0; mt < 2; ++mt) {
      const float4 b = ld4(P.b3 + 16*mt + 4*q);
      D[mt][0] = b.x; D[mt][1] = b.y; D[mt][2] = b.z; D[mt][3] = b.w;
    }
    #pragma unroll
    for (int kk = 0; kk < 2; ++kk) {
      const uint4 u = *reinterpret_cast<const uint4*>(xB + (size_t)s*128 + kk*64 + q*16);
      const int c = kk*32 + 8*q;
      const float4 scA = ld4(sc2 + c), shA = ld4(sh2 + c);
      const float4 scB = ld4(sc2 + c + 4), shB = ld4(sh2 + c + 4);
      const uint w[4] = {u.x,u.y,u.z,u.w};
      const float h0 = fmaxf(fmaf(bflo(w[0]), scA.x, shA.x), 0.f);
      const float h1 = fmaxf(fmaf(bfhi(w[0]), scA.y, shA.y), 0.f);
      const float h2 = fmaxf(fmaf(bflo(w[1]), scA.z, shA.z), 0.f);
      const float h3 = fmaxf(fmaf(bfhi(w[1]), scA.w, shA.w), 0.f);
      const float h4 = fmaxf(fmaf(bflo(w[2]), scB.x, shB.x), 0.f);
      const float h5 = fmaxf(fmaf(bfhi(w[2]), scB.y, shB.y), 0.f);
      const float h6 = fmaxf(fmaf(bflo(w[3]), scB.z, shB.z), 0.f);
      const float h7 = fmaxf(fmaf(bfhi(w[3]), scB.w, shB.w), 0.f);
      const bf16x8 bf = mkfrag(pk2(h0,h1), pk2(h2,h3), pk2(h4,h5), pk2(h6,h7));
      #pragma unroll
      for (int mt = 0; mt < 2; ++mt) {
        const bf16x8 af = ldfrag(w3fB + (size_t)((mt*2+kk)*64 + lane)*16);
        D[mt] = __builtin_amdgcn_mfma_f32_16x16x32_bf16(af, bf, D[mt], 0, 0, 0);
      }
    }
    #pragma unroll
    for (int mt = 0; mt < 2; ++mt) {
      #pragma unroll
      for (int r = 0; r < 4; ++r) {
        const float d = D[mt][r];
        sums[mt*4+r] += d;
        sqs[mt*4+r]  = fmaf(d, d, sqs[mt*4+r]);
      }
      const uint lo = pk2(D[mt][0], D[mt][1]);
      const uint hi = pk2(D[mt][2], D[mt][3]);
      *reinterpret_cast<uint2*>(xB + (size_t)s*128 + (16*mt + 4*q)*2) = make_uint2(lo, hi);
    }
  }
  #pragma unroll
  for (int d = 1; d <= 8; d <<= 1) {
    #pragma unroll
    for (int i = 0; i < 8; ++i) {
      sums[i] += __shfl_xor(sums[i], d, 64);
      sqs[i]  += __shfl_xor(sqs[i],  d, 64);
    }
  }
  if (m16 == 0) {
    #pragma unroll
    for (int i = 0; i < 8; ++i) {
      const int ch = 16*(i >> 2) + 4*q + (i & 3);
      atomicAdd(&sred[ch], sums[i]);
      atomicAdd(&sred[32+ch], sqs[i]);
    }
  }
  __syncthreads();
  if (threadIdx.x < 32) {
    float* stat = (float*)((char*)P.ws + OFF_STATS) + (size_t)(192 + threadIdx.x)*16;
    atomicAdd(stat, sred[threadIdx.x]);
    atomicAdd(stat + 8, sred[32+threadIdx.x]);
  }
}

__global__ __launch_bounds__(256) void k_l4n(Ptrs P) {
  const float* params = (const float*)((const char*)P.ws + OFF_PARAMS);
  const float* sc3 = params + 384, *sh3 = params + 416;
  const char* xB = (const char*)P.ws + OFF_X2;
  const unsigned stride = gridDim.x * 256;
  for (unsigned s = blockIdx.x*256 + threadIdx.x; s < BATCH; s += stride) {
    float z = P.b4[0];
    #pragma unroll
    for (int c16 = 0; c16 < 4; ++c16) {
      const uint4 u = *reinterpret_cast<const uint4*>(xB + (size_t)s*128 + c16*16);
      const uint w[4] = {u.x,u.y,u.z,u.w};
      #pragma unroll
      for (int j = 0; j < 4; ++j) {
        const int ch = c16*8 + 2*j;
        const float hlo = fmaxf(fmaf(bflo(w[j]), sc3[ch],   sh3[ch]),   0.f);
        const float hhi = fmaxf(fmaf(bfhi(w[j]), sc3[ch+1], sh3[ch+1]), 0.f);
        z = fmaf(hlo, P.W4[ch], z);
        z = fmaf(hhi, P.W4[ch+1], z);
      }
    }
    P.out[s] = 1.0f / (1.0f + __expf(-z));
  }
}

// -------- fallback (small ws): round-5 recompute path --------
__global__ __launch_bounds__(256) void k_l2r(Ptrs P) {
  __shared__ __align__(16) float Tl[68*TSTR];
  __shared__ float red[512];
  const float* params = (const float*)((const char*)P.ws + OFF_PARAMS);
  stage_tab(P.ws, params, Tl, true);
  const int lane = threadIdx.x & 63;
  float4 sums[16], sqs[16];
  #pragma unroll
  for (int j4 = 0; j4 < 16; ++j4) {
    sums[j4] = make_float4(0.f,0.f,0.f,0.f);
    sqs[j4]  = make_float4(0.f,0.f,0.f,0.f);
  }
  const unsigned stride = gridDim.x * 256;
  for (unsigned s = blockIdx.x*256 + threadIdx.x; s < BATCH; s += stride) {
    int rb[8]; float v[6];
    load_rb(P, s, rb, v);
    float4 acc[16];
    x2_from_lds(Tl, rb, v, P.W2, P.b2, acc);
    #pragma unroll
    for (int j4 = 0; j4 < 16; ++j4) {
      add4(sums[j4], acc[j4]);
      sqs[j4].x = fmaf(acc[j4].x, acc[j4].x, sqs[j4].x);
      sqs[j4].y = fmaf(acc[j4].y, acc[j4].y, sqs[j4].y);
      sqs[j4].z = fmaf(acc[j4].z, acc[j4].z, sqs[j4].z);
      sqs[j4].w = fmaf(acc[j4].w, acc[j4].w, sqs[j4].w);
    }
  }
  const float psum = bfly64_from<false>(sums, lane);
  const float psq  = bfly64_from<false>(sqs,  lane);
  red[threadIdx.x] = psum; red[256 + threadIdx.x] = psq;
  __syncthreads();
  const int t = threadIdx.x;
  if (t < 64) {
    const float s0 = red[t] + red[t+64] + red[t+128] + red[t+192];
    const float q0 = red[256+t] + red[256+t+64] + red[256+t+128] + red[256+t+192];
    float* stat = (float*)((char*)P.ws + OFF_STATS) + (size_t)(128 + t)*16;
    atomicAdd(stat, s0); atomicAdd(stat + 8, q0);
  }
}

__global__ __launch_bounds__(256) void k_l3_rec(Ptrs P) {
  __shared__ __align__(16) float Tl[68*TSTR];
  __shared__ float red[512];
  const float* params = (const float*)((const char*)P.ws + OFF_PARAMS);
  stage_tab(P.ws, params, Tl, true);
  const float* sc2 = params + 256, *sh2 = params + 320;
  const int lane = threadIdx.x & 63;
  float4 sums3[8], sqs3[8];
  #pragma unroll
  for (int j4 = 0; j4 < 8; ++j4) {
    sums3[j4] = make_float4(0.f,0.f,0.f,0.f);
    sqs3[j4]  = make_float4(0.f,0.f,0.f,0.f);
  }
  const unsigned stride = gridDim.x * 256;
  for (unsigned s = blockIdx.x*256 + threadIdx.x; s < BATCH; s += stride) {
    int rb[8]; float v[6];
    load_rb(P, s, rb, v);
    float4 acc2[16];
    x2_from_lds(Tl, rb, v, P.W2, P.b2, acc2);
    float4 acc3[8];
    x3_from_acc2(acc2, P, sc2, sh2, acc3);
    #pragma unroll
    for (int j4 = 0; j4 < 8; ++j4) {
      add4(sums3[j4], acc3[j4]);
      sqs3[j4].x = fmaf(acc3[j4].x, acc3[j4].x, sqs3[j4].x);
      sqs3[j4].y = fmaf(acc3[j4].y, acc3[j4].y, sqs3[j4].y);
      sqs3[j4].z = fmaf(acc3[j4].z, acc3[j4].z, sqs3[j4].z);
      sqs3[j4].w = fmaf(acc3[j4].w, acc3[j4].w, sqs3[j4].w);
    }
  }
  const float psum = bfly32_from<false>(sums3, lane);
  const float psq  = bfly32_from<false>(sqs3,  lane);
  red[threadIdx.x] = psum; red[256 + threadIdx.x] = psq;
  __syncthreads();
  const int t = threadIdx.x;
  if (t < 32) {
    const float s0 = red[t] + red[t+64] + red[t+128] + red[t+192];
    const float q0 = red[256+t] + red[256+t+64] + red[256+t+128] + red[256+t+192];
    float* stat = (float*)((char*)P.ws + OFF_STATS) + (size_t)(192 + t)*16;
    atomicAdd(stat, s0); atomicAdd(stat + 8, q0);
  }
}

__global__ __launch_bounds__(256) void k_l4_rec(Ptrs P) {
  __shared__ __align__(16) float Tl[68*TSTR];
  const float* params = (const float*)((const char*)P.ws + OFF_PARAMS);
  stage_tab(P.ws, params, Tl, true);
  const float* sc2 = params + 256, *sh2 = params + 320;
  const float* sc3 = params + 384, *sh3 = params + 416;
  const unsigned stride = gridDim.x * 256;
  for (unsigned s = blockIdx.x*256 + threadIdx.x; s < BATCH; s += stride) {
    int rb[8]; float v[6];
    load_rb(P, s, rb, v);
    float4 acc2[16];
    x2_from_lds(Tl, rb, v, P.W2, P.b2, acc2);
    float4 acc3[8];
    x3_from_acc2(acc2, P, sc2, sh2, acc3);
    float z = P.b4[0];
    #pragma unroll
    for (int k4 = 0; k4 < 8; ++k4) {
      const float4 a = acc3[k4];
      const float4 sc = ld4(sc3 + k4*4), sh = ld4(sh3 + k4*4);
      z = fmaf(fmaxf(fmaf(a.x, sc.x, sh.x), 0.0f), P.W4[k4*4+0], z);
      z = fmaf(fmaxf(fmaf(a.y, sc.y, sh.y), 0.0f), P.W4[k4*4+1], z);
      z = fmaf(fmaxf(fmaf(a.z, sc.z, sh.z), 0.0f), P.W4[k4*4+2], z);
      z = fmaf(fmaxf(fmaf(a.w, sc.w, sh.w), 0.0f), P.W4[k4*4+3], z);
    }
    P.out[s] = 1.0f / (1.0f + __expf(-z));
  }
}

// ---------------- host ----------------

extern "C" void kernel_launch(void* const* d_in, const int* in_sizes, int n_in,
                              void* d_out, int out_size, void* d_ws, size_t ws_size,
                              hipStream_t stream) {
  Ptrs P;
  P.br1 = (const int*)d_in[0];  P.sz1 = (const int*)d_in[1];
  P.en1 = (const int*)d_in[2];  P.tp1 = (const int*)d_in[3];
  P.ag1 = (const float*)d_in[4]; P.so1 = (const float*)d_in[5]; P.wt1 = (const float*)d_in[6];
  P.br2 = (const int*)d_in[7];  P.sz2 = (const int*)d_in[8];
  P.en2 = (const int*)d_in[9];  P.tp2 = (const int*)d_in[10];
  P.ag2 = (const float*)d_in[11]; P.so2 = (const float*)d_in[12]; P.wt2 = (const float*)d_in[13];
  P.bemb = (const float*)d_in[14]; P.temb = (const float*)d_in[15];
  P.W1 = (const float*)d_in[16]; P.b1 = (const float*)d_in[17];
  P.g1 = (const float*)d_in[18]; P.be1 = (const float*)d_in[19];
  P.W2 = (const float*)d_in[20]; P.b2 = (const float*)d_in[21];
  P.g2 = (const float*)d_in[22]; P.be2 = (const float*)d_in[23];
  P.W3 = (const float*)d_in[24]; P.b3 = (const float*)d_in[25];
  P.g3 = (const float*)d_in[26]; P.be3 = (const float*)d_in[27];
  P.W4 = (const float*)d_in[28]; P.b4 = (const float*)d_in[29];
  P.ws = (float*)d_ws; P.out = (float*)d_out;

  const bool t1 = ws_size >= T1_NEED;

  hipMemsetAsync((char*)d_ws + OFF_STATS, 0, 224*64, stream);
  hipLaunchKernelGGL(k_prep, dim3(1), dim3(256), 0, stream, P);
  hipLaunchKernelGGL(k_stats1, dim3(2048), dim3(256), 0, stream, P);
  hipLaunchKernelGGL(k_finalize, dim3(1), dim3(128), 0, stream, P, 128, 0, 0, P.g1, P.be1);
  if (t1) {
    hipLaunchKernelGGL(k_l2m, dim3(2048), dim3(256), 0, stream, P);
    hipLaunchKernelGGL(k_finalize, dim3(1), dim3(64), 0, stream, P, 64, 128, 256, P.g2, P.be2);
    hipLaunchKernelGGL(k_l3m, dim3(2048), dim3(256), 0, stream, P);
    hipLaunchKernelGGL(k_finalize, dim3(1), dim3(32), 0, stream, P, 32, 192, 384, P.g3, P.be3);
    hipLaunchKernelGGL(k_l4n, dim3(2048), dim3(256), 0, stream, P);
  } else {
    hipLaunchKernelGGL(k_l2r, dim3(1024), dim3(256), 0, stream, P);
    hipLaunchKernelGGL(k_finalize, dim3(1), dim3(64), 0, stream, P, 64, 128, 256, P.g2, P.be2);
    hipLaunchKernelGGL(k_l3_rec, dim3(1024), dim3(256), 0, stream, P);
    hipLaunchKernelGGL(k_finalize, dim3(1), dim3(32), 0, stream, P, 32, 192, 384, P.g3, P.be3);
    hipLaunchKernelGGL(k_l4_rec, dim3(2048), dim3(256), 0, stream, P);
  }
}

// Round 7
// 611.779 us; speedup vs baseline: 3.4421x; 1.4279x over previous
//
#include <hip/hip_runtime.h>
#include <hip/hip_bf16.h>

#define BATCH (1u<<20)
static constexpr float EPSBN = 1e-5f;
static constexpr float INV_B = 1.0f / (float)BATCH;

typedef unsigned int   uint;
typedef unsigned short ushort;

// f32 gather tables at ws+0, stride 132 floats.
// rows 0-14 breed1(+b1) | 15-23 temp1 | 24-38 breed2 | 39-47 temp2
// 48-50 sz1 | 51-53 en1 | 54-56 sz2 | 57-59 en2 | 60-65 continuous
#define TSTR 132
#define NTABROWS 66
#define TBSTR 136                      // bf16 table stride (elems)
#define OFF_TBF    36864ULL            // bf16 tables [66][136]
#define OFF_W2F    55296ULL            // W2^T A-frags bf16: 16*64*16B
#define OFF_W3F    71680ULL            // W3^T A-frags bf16: 4*64*16B
#define OFF_STATS  75776ULL            // 224 entries * 64B (sum @+0, sumsq @+32B)
#define OFF_PARAMS 90112ULL            // 448 f32: sc1@0 sh1@128 sc2@256 sh2@320 sc3@384 sh3@416
#define OFF_X2     98304ULL            // bf16 [B][64] 128B rows; x3 aliased into first 64B
#define T1_NEED    (98304ULL + 134217728ULL)

struct Ptrs {
  const int *br1,*sz1,*en1,*tp1; const float *ag1,*so1,*wt1;
  const int *br2,*sz2,*en2,*tp2; const float *ag2,*so2,*wt2;
  const float *bemb,*temb;
  const float *W1,*b1,*g1,*be1;
  const float *W2,*b2,*g2,*be2;
  const float *W3,*b3,*g3,*be3;
  const float *W4,*b4;
  float* ws; float* out;
};

typedef __attribute__((ext_vector_type(8))) short bf16x8;
typedef __attribute__((ext_vector_type(4))) float f32x4;

__device__ __forceinline__ float4 ld4(const float* p) {
  return *reinterpret_cast<const float4*>(p);
}
__device__ __forceinline__ void add4(float4& a, const float4 b) {
  a.x += b.x; a.y += b.y; a.z += b.z; a.w += b.w;
}
__device__ __forceinline__ void fma4s(float4& a, const float4 b, float s) {
  a.x = fmaf(b.x, s, a.x); a.y = fmaf(b.y, s, a.y);
  a.z = fmaf(b.z, s, a.z); a.w = fmaf(b.w, s, a.w);
}

__device__ __forceinline__ ushort bfb(float f) {
  union { __hip_bfloat16 h; ushort u; } cv; cv.h = __float2bfloat16(f); return cv.u;
}
__device__ __forceinline__ uint pk2(float a, float b) {
  return ((uint)bfb(b) << 16) | (uint)bfb(a);
}
__device__ __forceinline__ bf16x8 ldfrag(const void* p) {
  union { uint4 u; bf16x8 v; } cv; cv.u = *reinterpret_cast<const uint4*>(p); return cv.v;
}
__device__ __forceinline__ bf16x8 mkfrag(uint a, uint b, uint c, uint d) {
  union { uint4 u; bf16x8 v; } cv; cv.u = make_uint4(a,b,c,d); return cv.v;
}
__device__ __forceinline__ float bflo(uint w) { return __uint_as_float(w << 16); }
__device__ __forceinline__ float bfhi(uint w) { return __uint_as_float(w & 0xffff0000u); }

struct SIdx { int r[8]; float v[6]; };
__device__ __forceinline__ SIdx load_idx(const Ptrs& P, unsigned s) {
  SIdx o;
  o.r[0] = P.br1[s];      o.r[1] = 15 + P.tp1[s];
  o.r[2] = 24 + P.br2[s]; o.r[3] = 39 + P.tp2[s];
  o.r[4] = 48 + P.sz1[s]; o.r[5] = 51 + P.en1[s];
  o.r[6] = 54 + P.sz2[s]; o.r[7] = 57 + P.en2[s];
  o.v[0] = P.ag1[s]*(1.0f/15.0f); o.v[1] = P.so1[s]; o.v[2] = P.wt1[s]*0.01f;
  o.v[3] = P.ag2[s]*(1.0f/15.0f); o.v[4] = P.so2[s]; o.v[5] = P.wt2[s]*0.01f;
  return o;
}

// ---- rec-fallback helpers (only used if ws < T1_NEED) ----
__device__ __forceinline__ void load_rb(const Ptrs& P, unsigned s, int rb[8], float v[6]) {
  SIdx o = load_idx(P, s);
  #pragma unroll
  for (int i = 0; i < 8; ++i) rb[i] = o.r[i]*TSTR;
  #pragma unroll
  for (int i = 0; i < 6; ++i) v[i] = o.v[i];
}

__device__ __forceinline__ void stage_tab(const float* wsT, const float* params,
                                          float* Tl, bool bn1) {
  for (int i = threadIdx.x; i < NTABROWS*TSTR; i += blockDim.x) Tl[i] = wsT[i];
  if (bn1) {
    for (int i = threadIdx.x; i < 128; i += blockDim.x) {
      Tl[66*TSTR + i] = params[i];
      Tl[67*TSTR + i] = params[128 + i];
    }
  }
  __syncthreads();
}

__device__ __forceinline__ void x2_from_lds(const float* Tl, const int rb[8], const float v[6],
                                            const float* W2, const float* b2, float4 acc[16]) {
  #pragma unroll
  for (int j4 = 0; j4 < 16; ++j4) acc[j4] = ld4(b2 + j4*4);
  #pragma unroll 1
  for (int c4 = 0; c4 < 32; ++c4) {
    const int c = c4 * 4;
    float4 x = *reinterpret_cast<const float4*>(Tl + rb[0] + c);
    add4(x, *reinterpret_cast<const float4*>(Tl + rb[1] + c));
    add4(x, *reinterpret_cast<const float4*>(Tl + rb[2] + c));
    add4(x, *reinterpret_cast<const float4*>(Tl + rb[3] + c));
    add4(x, *reinterpret_cast<const float4*>(Tl + rb[4] + c));
    add4(x, *reinterpret_cast<const float4*>(Tl + rb[5] + c));
    add4(x, *reinterpret_cast<const float4*>(Tl + rb[6] + c));
    add4(x, *reinterpret_cast<const float4*>(Tl + rb[7] + c));
    #pragma unroll
    for (int m = 0; m < 6; ++m)
      fma4s(x, *reinterpret_cast<const float4*>(Tl + (60+m)*TSTR + c), v[m]);
    const float4 sc = *reinterpret_cast<const float4*>(Tl + 66*TSTR + c);
    const float4 sh = *reinterpret_cast<const float4*>(Tl + 67*TSTR + c);
    float hv[4];
    hv[0] = fmaxf(fmaf(x.x, sc.x, sh.x), 0.0f);
    hv[1] = fmaxf(fmaf(x.y, sc.y, sh.y), 0.0f);
    hv[2] = fmaxf(fmaf(x.z, sc.z, sh.z), 0.0f);
    hv[3] = fmaxf(fmaf(x.w, sc.w, sh.w), 0.0f);
    #pragma unroll
    for (int r = 0; r < 4; ++r) {
      const float hr = hv[r];
      const float4* w = reinterpret_cast<const float4*>(W2 + (c + r)*64);
      #pragma unroll
      for (int j4 = 0; j4 < 16; ++j4) fma4s(acc[j4], w[j4], hr);
    }
  }
}

__device__ __forceinline__ void x3_from_acc2(const float4 acc2[16], const Ptrs& P,
                                             const float* sc2, const float* sh2,
                                             float4 acc3[8]) {
  #pragma unroll
  for (int j4 = 0; j4 < 8; ++j4) acc3[j4] = ld4(P.b3 + j4*4);
  #pragma unroll
  for (int k4 = 0; k4 < 16; ++k4) {
    const float4 a = acc2[k4];
    const float4 sc = ld4(sc2 + k4*4), sh = ld4(sh2 + k4*4);
    const float hr[4] = {
      fmaxf(fmaf(a.x, sc.x, sh.x), 0.0f),
      fmaxf(fmaf(a.y, sc.y, sh.y), 0.0f),
      fmaxf(fmaf(a.z, sc.z, sh.z), 0.0f),
      fmaxf(fmaf(a.w, sc.w, sh.w), 0.0f)};
    #pragma unroll
    for (int r = 0; r < 4; ++r) {
      const float4* w = reinterpret_cast<const float4*>(P.W3 + (k4*4 + r)*32);
      #pragma unroll
      for (int j4 = 0; j4 < 8; ++j4) fma4s(acc3[j4], w[j4], hr[r]);
    }
  }
}

__device__ __forceinline__ float bfly_tail32(float st[32], int lane) {
#define BSTEP(D) { const bool h = (lane & D) != 0; \
  _Pragma("unroll") \
  for (int i = 0; i < D; ++i) { \
    float mine = h ? st[i] : st[i+D]; \
    float oth  = __shfl_xor(mine, D, 64); \
    float keep = h ? st[i+D] : st[i]; \
    st[i] = keep + oth; } }
  BSTEP(16) BSTEP(8) BSTEP(4) BSTEP(2) BSTEP(1)
#undef BSTEP
  return st[0];
}

template<bool SQ>
__device__ __forceinline__ float bfly64_from(const float4 acc[16], int lane) {
  float st[32];
  const bool hi = (lane & 32) != 0;
  #pragma unroll
  for (int j4 = 0; j4 < 8; ++j4) {
#define DO1(comp, idx) { \
    float lo = acc[j4].comp, hc = acc[j4+8].comp; \
    if (SQ) { lo *= lo; hc *= hc; } \
    float mine = hi ? lo : hc; \
    float keep = hi ? hc : lo; \
    st[4*j4+idx] = keep + __shfl_xor(mine, 32, 64); }
    DO1(x,0) DO1(y,1) DO1(z,2) DO1(w,3)
#undef DO1
  }
  return bfly_tail32(st, lane);
}

template<bool SQ>
__device__ __forceinline__ float bfly32_from(const float4 acc3[8], int lane) {
  float st[32];
  const bool hi = (lane & 32) != 0;
  #pragma unroll
  for (int j4 = 0; j4 < 8; ++j4) {
#define DO1(comp, idx) { \
    float vv = acc3[j4].comp; \
    if (SQ) vv *= vv; \
    float mine = hi ? vv : 0.0f; \
    float keep = hi ? 0.0f : vv; \
    st[4*j4+idx] = keep + __shfl_xor(mine, 32, 64); }
    DO1(x,0) DO1(y,1) DO1(z,2) DO1(w,3)
#undef DO1
  }
  return bfly_tail32(st, lane);
}

// ---------------- kernels ----------------

__global__ __launch_bounds__(256) void k_prep(Ptrs P) {
  const int t = threadIdx.x;
  float* T = P.ws;
  // zero stats (replaces hipMemsetAsync)
  {
    float* st = (float*)((char*)P.ws + OFF_STATS);
    for (int i = t; i < 224*16; i += 256) st[i] = 0.0f;
  }
  if (t < 128) {
    const int c = t;
    for (int b = 0; b < 15; ++b) {
      float a1 = P.b1[c], a2 = 0.0f;
      #pragma unroll
      for (int e = 0; e < 8; ++e) {
        a1 = fmaf(P.bemb[b*8+e], P.W1[e*128 + c], a1);
        a2 = fmaf(P.bemb[b*8+e], P.W1[(25+e)*128 + c], a2);
      }
      T[b*TSTR + c] = a1; T[(24+b)*TSTR + c] = a2;
    }
    for (int tt = 0; tt < 9; ++tt) {
      float a1 = 0.0f, a2 = 0.0f;
      #pragma unroll
      for (int e = 0; e < 8; ++e) {
        a1 = fmaf(P.temb[tt*8+e], P.W1[(14+e)*128 + c], a1);
        a2 = fmaf(P.temb[tt*8+e], P.W1[(39+e)*128 + c], a2);
      }
      T[(15+tt)*TSTR + c] = a1; T[(39+tt)*TSTR + c] = a2;
    }
    #pragma unroll
    for (int i = 0; i < 3; ++i) {
      T[(48+i)*TSTR + c] = P.W1[(8+i)*128 + c];
      T[(51+i)*TSTR + c] = P.W1[(11+i)*128 + c];
      T[(54+i)*TSTR + c] = P.W1[(33+i)*128 + c];
      T[(57+i)*TSTR + c] = P.W1[(36+i)*128 + c];
    }
    const int cr[6] = {22,23,24,47,48,49};
    #pragma unroll
    for (int m = 0; m < 6; ++m) T[(60+m)*TSTR + c] = P.W1[cr[m]*128 + c];
  }
  __syncthreads();
  __hip_bfloat16* Tb = (__hip_bfloat16*)((char*)P.ws + OFF_TBF);
  for (int idx = t; idx < 66*128; idx += 256) {
    const int r = idx >> 7, c = idx & 127;
    Tb[r*TBSTR + c] = __float2bfloat16(T[r*TSTR + c]);
  }
  __hip_bfloat16* w2f = (__hip_bfloat16*)((char*)P.ws + OFF_W2F);
  for (int slot = t; slot < 1024; slot += 256) {
    const int fid = slot >> 6, l = slot & 63;
    const int mt = fid >> 2, kk = fid & 3, q = l >> 4, m = l & 15;
    #pragma unroll
    for (int e = 0; e < 8; ++e)
      w2f[slot*8 + e] = __float2bfloat16(P.W2[(kk*32 + 8*q + e)*64 + 16*mt + m]);
  }
  __hip_bfloat16* w3f = (__hip_bfloat16*)((char*)P.ws + OFF_W3F);
  for (int slot = t; slot < 256; slot += 256) {
    const int fid = slot >> 6, l = slot & 63;
    const int mt = fid >> 1, kk = fid & 1, q = l >> 4, m = l & 15;
    #pragma unroll
    for (int e = 0; e < 8; ++e)
      w3f[slot*8 + e] = __float2bfloat16(P.W3[(kk*32 + 8*q + e)*32 + 16*mt + m]);
  }
}

// BN1 stats: 512-thr blocks; each WAVE specializes on one kk (32 channels)
// -> only 16 accumulator VGPRs per lane. bf16 tables in LDS.
__global__ __launch_bounds__(512) void k_stats1(Ptrs P) {
  __shared__ __align__(16) __hip_bfloat16 Tb[60*TBSTR];
  __shared__ float sred[256];
  {
    const uint* src = (const uint*)((const char*)P.ws + OFF_TBF);
    uint* dst = (uint*)Tb;
    for (int i = threadIdx.x; i < 60*TBSTR/2; i += 512) dst[i] = src[i];
  }
  if (threadIdx.x < 256) sred[threadIdx.x] = 0.f;
  __syncthreads();
  const int lane = threadIdx.x & 63;
  const int q = lane >> 4, m16 = lane & 15;
  const __hip_bfloat16* Tbc = (const __hip_bfloat16*)((const char*)P.ws + OFF_TBF);
  const unsigned gw = (blockIdx.x*512 + threadIdx.x) >> 6;
  const unsigned nw = (gridDim.x*512) >> 6;
  const int kk = gw & 3;
  const unsigned t0 = gw >> 2, ts = nw >> 2;
  const int c = kk*32 + 8*q;
  float sums[8], sqs[8];
  #pragma unroll
  for (int i = 0; i < 8; ++i) { sums[i] = 0.f; sqs[i] = 0.f; }
  for (unsigned tt = t0; tt < (BATCH>>4); tt += ts) {
    const unsigned s = tt*16 + m16;
    const SIdx o = load_idx(P, s);
    float x[8];
    #pragma unroll
    for (int e = 0; e < 8; ++e) x[e] = 0.f;
    #pragma unroll
    for (int g = 0; g < 8; ++g) {
      const uint4 u = *reinterpret_cast<const uint4*>(Tb + o.r[g]*TBSTR + c);
      const uint w[4] = {u.x,u.y,u.z,u.w};
      #pragma unroll
      for (int j = 0; j < 4; ++j) { x[2*j] += bflo(w[j]); x[2*j+1] += bfhi(w[j]); }
    }
    #pragma unroll
    for (int m = 0; m < 6; ++m) {
      const uint4 u = *reinterpret_cast<const uint4*>(Tbc + (60+m)*TBSTR + c);
      const uint w[4] = {u.x,u.y,u.z,u.w};
      #pragma unroll
      for (int j = 0; j < 4; ++j) {
        x[2*j]   = fmaf(bflo(w[j]), o.v[m], x[2*j]);
        x[2*j+1] = fmaf(bfhi(w[j]), o.v[m], x[2*j+1]);
      }
    }
    #pragma unroll
    for (int e = 0; e < 8; ++e) {
      sums[e] += x[e];
      sqs[e]   = fmaf(x[e], x[e], sqs[e]);
    }
  }
  #pragma unroll
  for (int d = 1; d <= 8; d <<= 1) {
    #pragma unroll
    for (int i = 0; i < 8; ++i) {
      sums[i] += __shfl_xor(sums[i], d, 64);
      sqs[i]  += __shfl_xor(sqs[i],  d, 64);
    }
  }
  if (m16 == 0) {
    #pragma unroll
    for (int e = 0; e < 8; ++e) {
      atomicAdd(&sred[c + e], sums[e]);
      atomicAdd(&sred[128 + c + e], sqs[e]);
    }
  }
  __syncthreads();
  if (threadIdx.x < 128) {
    float* stat = (float*)((char*)P.ws + OFF_STATS) + (size_t)threadIdx.x*16;
    atomicAdd(stat,     sred[threadIdx.x]);
    atomicAdd(stat + 8, sred[128+threadIdx.x]);
  }
}

__global__ void k_finalize(Ptrs P, int nch, int entry0, int pofs,
                           const float* g, const float* be) {
  const int c = threadIdx.x;
  if (c >= nch) return;
  const float* stat = (const float*)((const char*)P.ws + OFF_STATS) + (size_t)(entry0 + c)*16;
  const float mean = stat[0] * INV_B;
  const float var  = stat[8] * INV_B - mean*mean;
  const float inv  = 1.0f / sqrtf(var + EPSBN);
  const float scale = g[c] * inv;
  float* params = (float*)((char*)P.ws + OFF_PARAMS);
  params[pofs + c]       = scale;
  params[pofs + nch + c] = be[c] - mean * scale;
}

// Layer2 MFMA: 512-thr blocks sharing one f32 table copy; index prefetch;
// NO stats (separate k_stats2). lane=(sample m16, k-slice q).
__global__ __launch_bounds__(512) void k_l2m(Ptrs P) {
  __shared__ __align__(16) float Tl[60*TSTR];
  for (int i = threadIdx.x; i < 60*TSTR; i += 512) Tl[i] = P.ws[i];
  __syncthreads();
  const float* params = (const float*)((const char*)P.ws + OFF_PARAMS);
  const float* sc1 = params, *sh1 = params + 128;
  const float* contT = P.ws;            // rows 60..65 from global (L1-hot)
  const int lane = threadIdx.x & 63;
  const int q = lane >> 4, m16 = lane & 15;
  const char* w2fB = (const char*)P.ws + OFF_W2F;
  char* x2B = (char*)P.ws + OFF_X2;
  const unsigned nw = (gridDim.x*512) >> 6;
  const unsigned NT = BATCH >> 4;
  unsigned it = (blockIdx.x*512 + threadIdx.x) >> 6;
  if (it >= NT) return;
  SIdx cur = load_idx(P, it*16 + m16);
  while (true) {
    const unsigned itn = it + nw;
    const bool more = itn < NT;
    SIdx nxt;
    if (more) nxt = load_idx(P, itn*16 + m16);   // prefetch next tile's indices
    const unsigned s = it*16 + m16;
    int rb[8];
    #pragma unroll
    for (int i = 0; i < 8; ++i) rb[i] = cur.r[i]*TSTR;
    f32x4 D[4];
    #pragma unroll
    for (int mt = 0; mt < 4; ++mt) {
      const float4 b = ld4(P.b2 + 16*mt + 4*q);
      D[mt][0] = b.x; D[mt][1] = b.y; D[mt][2] = b.z; D[mt][3] = b.w;
    }
    #pragma unroll
    for (int kk = 0; kk < 4; ++kk) {
      const int c = kk*32 + 8*q;
      float4 xa = ld4(Tl + rb[0] + c);
      float4 xb = ld4(Tl + rb[0] + c + 4);
      #pragma unroll
      for (int g = 1; g < 8; ++g) {
        add4(xa, ld4(Tl + rb[g] + c));
        add4(xb, ld4(Tl + rb[g] + c + 4));
      }
      #pragma unroll
      for (int m = 0; m < 6; ++m) {
        fma4s(xa, ld4(contT + (60+m)*TSTR + c), cur.v[m]);
        fma4s(xb, ld4(contT + (60+m)*TSTR + c + 4), cur.v[m]);
      }
      const float4 sca = ld4(sc1 + c), sha = ld4(sh1 + c);
      const float4 scb = ld4(sc1 + c + 4), shb = ld4(sh1 + c + 4);
      const float h0 = fmaxf(fmaf(xa.x, sca.x, sha.x), 0.f);
      const float h1 = fmaxf(fmaf(xa.y, sca.y, sha.y), 0.f);
      const float h2 = fmaxf(fmaf(xa.z, sca.z, sha.z), 0.f);
      const float h3 = fmaxf(fmaf(xa.w, sca.w, sha.w), 0.f);
      const float h4 = fmaxf(fmaf(xb.x, scb.x, shb.x), 0.f);
      const float h5 = fmaxf(fmaf(xb.y, scb.y, shb.y), 0.f);
      const float h6 = fmaxf(fmaf(xb.z, scb.z, shb.z), 0.f);
      const float h7 = fmaxf(fmaf(xb.w, scb.w, shb.w), 0.f);
      const bf16x8 bf = mkfrag(pk2(h0,h1), pk2(h2,h3), pk2(h4,h5), pk2(h6,h7));
      #pragma unroll
      for (int mt = 0; mt < 4; ++mt) {
        const bf16x8 af = ldfrag(w2fB + (size_t)((mt*4+kk)*64 + lane)*16);
        D[mt] = __builtin_amdgcn_mfma_f32_16x16x32_bf16(af, bf, D[mt], 0, 0, 0);
      }
    }
    #pragma unroll
    for (int mt = 0; mt < 4; ++mt) {
      const uint lo = pk2(D[mt][0], D[mt][1]);
      const uint hi = pk2(D[mt][2], D[mt][3]);
      *reinterpret_cast<uint2*>(x2B + (size_t)s*128 + (16*mt + 4*q)*2) = make_uint2(lo, hi);
    }
    if (!more) break;
    cur = nxt; it = itn;
  }
}

// BN2 stats from stored bf16 x2 (consistent with what l3 consumes). BW-bound.
__global__ __launch_bounds__(256) void k_stats2(Ptrs P) {
  const uint* x2u = (const uint*)((const char*)P.ws + OFF_X2);
  const int pid = threadIdx.x & 31;         // channel pair (2 ch)
  const int lane = threadIdx.x & 63;
  const int w = threadIdx.x >> 6;
  float slo = 0.f, shi = 0.f, qlo = 0.f, qhi = 0.f;
  const unsigned r0 = blockIdx.x*8 + (threadIdx.x >> 5);
  const unsigned rs = gridDim.x*8;
  #pragma unroll 4
  for (unsigned r = r0; r < BATCH; r += rs) {
    const uint u = x2u[(size_t)r*32 + pid];
    const float lo = bflo(u), hi = bfhi(u);
    slo += lo; shi += hi;
    qlo = fmaf(lo, lo, qlo); qhi = fmaf(hi, hi, qhi);
  }
  slo += __shfl_xor(slo, 32, 64); shi += __shfl_xor(shi, 32, 64);
  qlo += __shfl_xor(qlo, 32, 64); qhi += __shfl_xor(qhi, 32, 64);
  __shared__ float red[512];
  if (lane < 32) {
    red[w*64 + 2*pid]       = slo; red[w*64 + 2*pid + 1]       = shi;
    red[256 + w*64 + 2*pid] = qlo; red[256 + w*64 + 2*pid + 1] = qhi;
  }
  __syncthreads();
  if (threadIdx.x < 64) {
    const int c = threadIdx.x;
    const float s  = red[c] + red[64+c] + red[128+c] + red[192+c];
    const float qq = red[256+c] + red[320+c] + red[384+c] + red[448+c];
    float* stat = (float*)((char*)P.ws + OFF_STATS) + (size_t)(128 + c)*16;
    atomicAdd(stat, s); atomicAdd(stat + 8, qq);
  }
}

// Layer3 MFMA: lean (no stats), x2 prefetch.
__global__ __launch_bounds__(256) void k_l3m(Ptrs P) {
  const float* params = (const float*)((const char*)P.ws + OFF_PARAMS);
  const float* sc2 = params + 256, *sh2 = params + 320;
  const int lane = threadIdx.x & 63;
  const int q = lane >> 4, m16 = lane & 15;
  const char* w3fB = (const char*)P.ws + OFF_W3F;
  char* xB = (char*)P.ws + OFF_X2;
  const unsigned nw = (gridDim.x*256) >> 6;
  const unsigned NT = BATCH >> 4;
  unsigned it = (blockIdx.x*256 + threadIdx.x) >> 6;
  if (it >= NT) return;
  unsigned s = it*16 + m16;
  uint4 u0 = *reinterpret_cast<const uint4*>(xB + (size_t)s*128 + q*16);
  uint4 u1 = *reinterpret_cast<const uint4*>(xB + (size_t)s*128 + 64 + q*16);
  while (true) {
    const unsigned itn = it + nw;
    const bool more = itn < NT;
    uint4 n0, n1;
    if (more) {
      const unsigned sn = itn*16 + m16;
      n0 = *reinterpret_cast<const uint4*>(xB + (size_t)sn*128 + q*16);
      n1 = *reinterpret_cast<const uint4*>(xB + (size_t)sn*128 + 64 + q*16);
    }
    f32x4 D[2];
    #pragma unroll
    for (int mt = 0; mt < 2; ++mt) {
      const float4 b = ld4(P.b3 + 16*mt + 4*q);
      D[mt][0] = b.x; D[mt][1] = b.y; D[mt][2] = b.z; D[mt][3] = b.w;
    }
    #pragma unroll
    for (int kk = 0; kk < 2; ++kk) {
      const uint4 u = (kk == 0) ? u0 : u1;
      const int c = kk*32 + 8*q;
      const float4 scA = ld4(sc2 + c), shA = ld4(sh2 + c);
      const float4 scB = ld4(sc2 + c + 4), shB = ld4(sh2 + c + 4);
      const uint w[4] = {u.x,u.y,u.z,u.w};
      const float h0 = fmaxf(fmaf(bflo(w[0]), scA.x, shA.x), 0.f);
      const float h1 = fmaxf(fmaf(bfhi(w[0]), scA.y, shA.y), 0.f);
      const float h2 = fmaxf(fmaf(bflo(w[1]), scA.z, shA.z), 0.f);
      const float h3 = fmaxf(fmaf(bfhi(w[1]), scA.w, shA.w), 0.f);
      const float h4 = fmaxf(fmaf(bflo(w[2]), scB.x, shB.x), 0.f);
      const float h5 = fmaxf(fmaf(bfhi(w[2]), scB.y, shB.y), 0.f);
      const float h6 = fmaxf(fmaf(bflo(w[3]), scB.z, shB.z), 0.f);
      const float h7 = fmaxf(fmaf(bfhi(w[3]), scB.w, shB.w), 0.f);
      const bf16x8 bf = mkfrag(pk2(h0,h1), pk2(h2,h3), pk2(h4,h5), pk2(h6,h7));
      #pragma unroll
      for (int mt = 0; mt < 2; ++mt) {
        const bf16x8 af = ldfrag(w3fB + (size_t)((mt*2+kk)*64 + lane)*16);
        D[mt] = __builtin_amdgcn_mfma_f32_16x16x32_bf16(af, bf, D[mt], 0, 0, 0);
      }
    }
    #pragma unroll
    for (int mt = 0; mt < 2; ++mt) {
      const uint lo = pk2(D[mt][0], D[mt][1]);
      const uint hi = pk2(D[mt][2], D[mt][3]);
      *reinterpret_cast<uint2*>(xB + (size_t)s*128 + (16*mt + 4*q)*2) = make_uint2(lo, hi);
    }
    if (!more) break;
    u0 = n0; u1 = n1; it = itn; s = it*16 + m16;
  }
}

// BN3 stats from stored bf16 x3 (first 64B of each 128B row).
__global__ __launch_bounds__(256) void k_stats3(Ptrs P) {
  const uint* xu = (const uint*)((const char*)P.ws + OFF_X2);
  const int pid = threadIdx.x & 15;        // channel pair (2 ch), 16 pairs = 32 ch
  const int lane = threadIdx.x & 63;
  const int w = threadIdx.x >> 6;
  float slo = 0.f, shi = 0.f, qlo = 0.f, qhi = 0.f;
  const unsigned r0 = blockIdx.x*16 + (threadIdx.x >> 4);
  const unsigned rs = gridDim.x*16;
  #pragma unroll 4
  for (unsigned r = r0; r < BATCH; r += rs) {
    const uint u = xu[(size_t)r*32 + pid];
    const float lo = bflo(u), hi = bfhi(u);
    slo += lo; shi += hi;
    qlo = fmaf(lo, lo, qlo); qhi = fmaf(hi, hi, qhi);
  }
  #pragma unroll
  for (int d = 16; d <= 32; d <<= 1) {
    slo += __shfl_xor(slo, d, 64); shi += __shfl_xor(shi, d, 64);
    qlo += __shfl_xor(qlo, d, 64); qhi += __shfl_xor(qhi, d, 64);
  }
  __shared__ float red[256];
  if (lane < 16) {
    red[w*32 + 2*pid]       = slo; red[w*32 + 2*pid + 1]       = shi;
    red[128 + w*32 + 2*pid] = qlo; red[128 + w*32 + 2*pid + 1] = qhi;
  }
  __syncthreads();
  if (threadIdx.x < 32) {
    const int c = threadIdx.x;
    const float s  = red[c] + red[32+c] + red[64+c] + red[96+c];
    const float qq = red[128+c] + red[160+c] + red[192+c] + red[224+c];
    float* stat = (float*)((char*)P.ws + OFF_STATS) + (size_t)(192 + c)*16;
    atomicAdd(stat, s); atomicAdd(stat + 8, qq);
  }
}

__global__ __launch_bounds__(256) void k_l4n(Ptrs P) {
  const float* params = (const float*)((const char*)P.ws + OFF_PARAMS);
  const float* sc3 = params + 384, *sh3 = params + 416;
  const char* xB = (const char*)P.ws + OFF_X2;
  const unsigned stride = gridDim.x * 256;
  for (unsigned s = blockIdx.x*256 + threadIdx.x; s < BATCH; s += stride) {
    float z = P.b4[0];
    #pragma unroll
    for (int c16 = 0; c16 < 4; ++c16) {
      const uint4 u = *reinterpret_cast<const uint4*>(xB + (size_t)s*128 + c16*16);
      const uint w[4] = {u.x,u.y,u.z,u.w};
      #pragma unroll
      for (int j = 0; j < 4; ++j) {
        const int ch = c16*8 + 2*j;
        const float hlo = fmaxf(fmaf(bflo(w[j]), sc3[ch],   sh3[ch]),   0.f);
        const float hhi = fmaxf(fmaf(bfhi(w[j]), sc3[ch+1], sh3[ch+1]), 0.f);
        z = fmaf(hlo, P.W4[ch], z);
        z = fmaf(hhi, P.W4[ch+1], z);
      }
    }
    P.out[s] = 1.0f / (1.0f + __expf(-z));
  }
}

// -------- fallback (small ws): recompute path --------
__global__ __launch_bounds__(256) void k_l2r(Ptrs P) {
  __shared__ __align__(16) float Tl[68*TSTR];
  __shared__ float red[512];
  const float* params = (const float*)((const char*)P.ws + OFF_PARAMS);
  stage_tab(P.ws, params, Tl, true);
  const int lane = threadIdx.x & 63;
  float4 sums[16], sqs[16];
  #pragma unroll
  for (int j4 = 0; j4 < 16; ++j4) {
    sums[j4] = make_float4(0.f,0.f,0.f,0.f);
    sqs[j4]  = make_float4(0.f,0.f,0.f,0.f);
  }
  const unsigned stride = gridDim.x * 256;
  for (unsigned s = blockIdx.x*256 + threadIdx.x; s < BATCH; s += stride) {
    int rb[8]; float v[6];
    load_rb(P, s, rb, v);
    float4 acc[16];
    x2_from_lds(Tl, rb, v, P.W2, P.b2, acc);
    #pragma unroll
    for (int j4 = 0; j4 < 16; ++j4) {
      add4(sums[j4], acc[j4]);
      sqs[j4].x = fmaf(acc[j4].x, acc[j4].x, sqs[j4].x);
      sqs[j4].y = fmaf(acc[j4].y, acc[j4].y, sqs[j4].y);
      sqs[j4].z = fmaf(acc[j4].z, acc[j4].z, sqs[j4].z);
      sqs[j4].w = fmaf(acc[j4].w, acc[j4].w, sqs[j4].w);
    }
  }
  const float psum = bfly64_from<false>(sums, lane);
  const float psq  = bfly64_from<false>(sqs,  lane);
  red[threadIdx.x] = psum; red[256 + threadIdx.x] = psq;
  __syncthreads();
  const int t = threadIdx.x;
  if (t < 64) {
    const float s0 = red[t] + red[t+64] + red[t+128] + red[t+192];
    const float q0 = red[256+t] + red[256+t+64] + red[256+t+128] + red[256+t+192];
    float* stat = (float*)((char*)P.ws + OFF_STATS) + (size_t)(128 + t)*16;
    atomicAdd(stat, s0); atomicAdd(stat + 8, q0);
  }
}

__global__ __launch_bounds__(256) void k_l3_rec(Ptrs P) {
  __shared__ __align__(16) float Tl[68*TSTR];
  __shared__ float red[512];
  const float* params = (const float*)((const char*)P.ws + OFF_PARAMS);
  stage_tab(P.ws, params, Tl, true);
  const float* sc2 = params + 256, *sh2 = params + 320;
  const int lane = threadIdx.x & 63;
  float4 sums3[8], sqs3[8];
  #pragma unroll
  for (int j4 = 0; j4 < 8; ++j4) {
    sums3[j4] = make_float4(0.f,0.f,0.f,0.f);
    sqs3[j4]  = make_float4(0.f,0.f,0.f,0.f);
  }
  const unsigned stride = gridDim.x * 256;
  for (unsigned s = blockIdx.x*256 + threadIdx.x; s < BATCH; s += stride) {
    int rb[8]; float v[6];
    load_rb(P, s, rb, v);
    float4 acc2[16];
    x2_from_lds(Tl, rb, v, P.W2, P.b2, acc2);
    float4 acc3[8];
    x3_from_acc2(acc2, P, sc2, sh2, acc3);
    #pragma unroll
    for (int j4 = 0; j4 < 8; ++j4) {
      add4(sums3[j4], acc3[j4]);
      sqs3[j4].x = fmaf(acc3[j4].x, acc3[j4].x, sqs3[j4].x);
      sqs3[j4].y = fmaf(acc3[j4].y, acc3[j4].y, sqs3[j4].y);
      sqs3[j4].z = fmaf(acc3[j4].z, acc3[j4].z, sqs3[j4].z);
      sqs3[j4].w = fmaf(acc3[j4].w, acc3[j4].w, sqs3[j4].w);
    }
  }
  const float psum = bfly32_from<false>(sums3, lane);
  const float psq  = bfly32_from<false>(sqs3,  lane);
  red[threadIdx.x] = psum; red[256 + threadIdx.x] = psq;
  __syncthreads();
  const int t = threadIdx.x;
  if (t < 32) {
    const float s0 = red[t] + red[t+64] + red[t+128] + red[t+192];
    const float q0 = red[256+t] + red[256+t+64] + red[256+t+128] + red[256+t+192];
    float* stat = (float*)((char*)P.ws + OFF_STATS) + (size_t)(192 + t)*16;
    atomicAdd(stat, s0); atomicAdd(stat + 8, q0);
  }
}

__global__ __launch_bounds__(256) void k_l4_rec(Ptrs P) {
  __shared__ __align__(16) float Tl[68*TSTR];
  const float* params = (const float*)((const char*)P.ws + OFF_PARAMS);
  stage_tab(P.ws, params, Tl, true);
  const float* sc2 = params + 256, *sh2 = params + 320;
  const float* sc3 = params + 384, *sh3 = params + 416;
  const unsigned stride = gridDim.x * 256;
  for (unsigned s = blockIdx.x*256 + threadIdx.x; s < BATCH; s += stride) {
    int rb[8]; float v[6];
    load_rb(P, s, rb, v);
    float4 acc2[16];
    x2_from_lds(Tl, rb, v, P.W2, P.b2, acc2);
    float4 acc3[8];
    x3_from_acc2(acc2, P, sc2, sh2, acc3);
    float z = P.b4[0];
    #pragma unroll
    for (int k4 = 0; k4 < 8; ++k4) {
      const float4 a = acc3[k4];
      const float4 sc = ld4(sc3 + k4*4), sh = ld4(sh3 + k4*4);
      z = fmaf(fmaxf(fmaf(a.x, sc.x, sh.x), 0.0f), P.W4[k4*4+0], z);
      z = fmaf(fmaxf(fmaf(a.y, sc.y, sh.y), 0.0f), P.W4[k4*4+1], z);
      z = fmaf(fmaxf(fmaf(a.z, sc.z, sh.z), 0.0f), P.W4[k4*4+2], z);
      z = fmaf(fmaxf(fmaf(a.w, sc.w, sh.w), 0.0f), P.W4[k4*4+3], z);
    }
    P.out[s] = 1.0f / (1.0f + __expf(-z));
  }
}

// ---------------- host ----------------

extern "C" void kernel_launch(void* const* d_in, const int* in_sizes, int n_in,
                              void* d_out, int out_size, void* d_ws, size_t ws_size,
                              hipStream_t stream) {
  Ptrs P;
  P.br1 = (const int*)d_in[0];  P.sz1 = (const int*)d_in[1];
  P.en1 = (const int*)d_in[2];  P.tp1 = (const int*)d_in[3];
  P.ag1 = (const float*)d_in[4]; P.so1 = (const float*)d_in[5]; P.wt1 = (const float*)d_in[6];
  P.br2 = (const int*)d_in[7];  P.sz2 = (const int*)d_in[8];
  P.en2 = (const int*)d_in[9];  P.tp2 = (const int*)d_in[10];
  P.ag2 = (const float*)d_in[11]; P.so2 = (const float*)d_in[12]; P.wt2 = (const float*)d_in[13];
  P.bemb = (const float*)d_in[14]; P.temb = (const float*)d_in[15];
  P.W1 = (const float*)d_in[16]; P.b1 = (const float*)d_in[17];
  P.g1 = (const float*)d_in[18]; P.be1 = (const float*)d_in[19];
  P.W2 = (const float*)d_in[20]; P.b2 = (const float*)d_in[21];
  P.g2 = (const float*)d_in[22]; P.be2 = (const float*)d_in[23];
  P.W3 = (const float*)d_in[24]; P.b3 = (const float*)d_in[25];
  P.g3 = (const float*)d_in[26]; P.be3 = (const float*)d_in[27];
  P.W4 = (const float*)d_in[28]; P.b4 = (const float*)d_in[29];
  P.ws = (float*)d_ws; P.out = (float*)d_out;

  const bool t1 = ws_size >= T1_NEED;

  hipLaunchKernelGGL(k_prep, dim3(1), dim3(256), 0, stream, P);
  hipLaunchKernelGGL(k_stats1, dim3(1024), dim3(512), 0, stream, P);
  hipLaunchKernelGGL(k_finalize, dim3(1), dim3(128), 0, stream, P, 128, 0, 0, P.g1, P.be1);
  if (t1) {
    hipLaunchKernelGGL(k_l2m, dim3(1024), dim3(512), 0, stream, P);
    hipLaunchKernelGGL(k_stats2, dim3(1024), dim3(256), 0, stream, P);
    hipLaunchKernelGGL(k_finalize, dim3(1), dim3(64), 0, stream, P, 64, 128, 256, P.g2, P.be2);
    hipLaunchKernelGGL(k_l3m, dim3(2048), dim3(256), 0, stream, P);
    hipLaunchKernelGGL(k_stats3, dim3(1024), dim3(256), 0, stream, P);
    hipLaunchKernelGGL(k_finalize, dim3(1), dim3(32), 0, stream, P, 32, 192, 384, P.g3, P.be3);
    hipLaunchKernelGGL(k_l4n, dim3(2048), dim3(256), 0, stream, P);
  } else {
    hipLaunchKernelGGL(k_l2r, dim3(1024), dim3(256), 0, stream, P);
    hipLaunchKernelGGL(k_finalize, dim3(1), dim3(64), 0, stream, P, 64, 128, 256, P.g2, P.be2);
    hipLaunchKernelGGL(k_l3_rec, dim3(1024), dim3(256), 0, stream, P);
    hipLaunchKernelGGL(k_finalize, dim3(1), dim3(32), 0, stream, P, 32, 192, 384, P.g3, P.be3);
    hipLaunchKernelGGL(k_l4_rec, dim3(2048), dim3(256), 0, stream, P);
  }
}